// Round 13
// baseline (4313.726 us; speedup 1.0000x reference)
//
#include <hip/hip_runtime.h>

#define DI __device__ __forceinline__
DI float silu_f(float x){ return x * (1.0f/(1.0f+__expf(-x))); }

template<int X> struct LOG2 { static constexpr int v = 1 + LOG2<X/2>::v; };
template<> struct LOG2<1> { static constexpr int v = 0; };

// ---------------------------------------------------------------------------
// Direct conv, NHWC in, HWIO weights, LDS-staged weight slices (r8 config).
// Thread = NPIX pixels x 4 co. G: ci-split (FROZEN — VQ argmin is sensitive
// to latent rounding). CS: co-split across blocks (numerics-free).
// r13: cross-tap input prefetch for CLEN<=16 layers (conv1/conv2/conv3):
// at tap kx, issue tap kx+1's global va loads into a 2-buffer register file
// (statically indexed via unrolled kx), then run tap kx's ds_read+FMA.
// Hides ~200cy global latency under a full tap of compute. FMA chain order
// per output (ky->kx->ci asc->r asc) UNCHANGED -> bit-identical (r12 A/B
// proved latency-bound, not issue-bound: pk_fma was neutral).
// CLEN>16 layers keep the r8-exact unroll-2 inner loop (134us-proven).
// ---------------------------------------------------------------------------
template<int KH,int KW,int STRIDE,int PAD,int CIN,int COUT,int NPIX,
         bool ACT,bool BIAS,int G,int CS>
__global__ __launch_bounds__(256) void conv_k(
    const float* __restrict__ in, const float* __restrict__ w,
    const float* __restrict__ bias, float* __restrict__ out,
    int N,int H,int W,int OH,int OW)
{
  constexpr int CLEN = CIN/G;
  constexpr int COB  = COUT/CS;
  constexpr int COQ  = COB/4;
  constexpr int GSH  = LOG2<G>::v;
  constexpr int CSH  = LOG2<CS>::v;
  constexpr int TAPF = CLEN*COB;
  constexpr bool SALL = (KH*KW*TAPF*4) <= 47*1024;
  constexpr int NTAP = SALL ? KH*KW : KW;
  static_assert(CLEN==3 || (CLEN%4)==0, "ci");
  __shared__ float sw[NTAP*TAPF];

  const int g  = blockIdx.x & (G-1);
  const int cs = (blockIdx.x >> GSH) & (CS-1);
  const int bx = blockIdx.x >> (GSH+CSH);
  const int total = N*OH*OW;
  if (G>1) out += (size_t)g * total * COUT;
  const int ci_off  = g*CLEN;
  const int co_base = cs*COB;

  int idx = bx*256 + (int)threadIdx.x;
  int cq = idx % COQ;
  int pg = idx / COQ;
  int co = cq*4;                 // within block's co slice
  int gco = co_base + co;        // global co
  int p0 = pg*NPIX;

  float acc[NPIX][4] = {};
  int iy0[NPIX], ix0[NPIX]; const float* base[NPIX]; bool pv[NPIX];
#pragma unroll
  for (int t=0;t<NPIX;t++){
    int p=p0+t; pv[t]=(p<total); int pp=pv[t]?p:0;
    int ox=pp%OW; int r=pp/OW; int oy=r%OH; int n=r/OH;
    iy0[t]=oy*STRIDE-PAD; ix0[t]=ox*STRIDE-PAD;
    base[t]=in+(size_t)n*H*W*CIN + ci_off;
  }

  auto stage = [&](int tap0){
    constexpr int TQ = TAPF/4;
    constexpr int V  = NTAP*TQ;
    for (int v=threadIdx.x; v<V; v+=256){
      int tap = v / TQ; int rem = v - tap*TQ;
      float4 q;
      if constexpr (CS==1){
        const float4* src = (const float4*)(w + ((size_t)(tap0+tap)*CIN + ci_off)*COUT);
        q = src[rem];
      } else {
        int ci = rem / (COB/4); int r2 = rem - ci*(COB/4);
        q = *(const float4*)(w + ((size_t)(tap0+tap)*CIN + ci_off + ci)*COUT
                               + co_base + r2*4);
      }
      *(float4*)(sw + (size_t)tap*TAPF + rem*4) = q;
    }
  };

  if constexpr (SALL){
    stage(0);
    __syncthreads();
  }

  for (int ky=0; ky<KH; ky++){
    if constexpr (!SALL){
      __syncthreads();
      stage(ky*KW);
      __syncthreads();
    }
    const float* swr = SALL ? sw + (size_t)ky*KW*TAPF : sw;

    if constexpr (CLEN==3){
      // pipelined: 2-buffer cross-tap prefetch (scalar loads)
      float va[2][NPIX][3];
      auto ldtap = [&](int kx, int buf){
#pragma unroll
        for (int t=0;t<NPIX;t++){
          int iy=iy0[t]+ky, ix=ix0[t]+kx;
          bool ok = pv[t] && iy>=0 && iy<H && ix>=0 && ix<W;
          const float* ip = base[t]+(size_t)(iy*W+ix)*CIN;
          va[buf][t][0]=ok?ip[0]:0.f;
          va[buf][t][1]=ok?ip[1]:0.f;
          va[buf][t][2]=ok?ip[2]:0.f;
        }
      };
      ldtap(0,0);
#pragma unroll
      for (int kx=0; kx<KW; kx++){
        const int cur = kx&1;
        if (kx+1<KW) ldtap(kx+1, cur^1);
        const float* swt = swr + (size_t)kx*TAPF;
        float wv[3][4];
        *(float4*)wv[0]=*(const float4*)(swt + 0*COB + co);
        *(float4*)wv[1]=*(const float4*)(swt + 1*COB + co);
        *(float4*)wv[2]=*(const float4*)(swt + 2*COB + co);
#pragma unroll
        for (int t=0;t<NPIX;t++)
#pragma unroll
          for (int j=0;j<4;j++)
            acc[t][j]=fmaf(va[cur][t][0],wv[0][j],
                      fmaf(va[cur][t][1],wv[1][j],
                      fmaf(va[cur][t][2],wv[2][j],acc[t][j])));
      }
    } else if constexpr (CLEN<=16){
      // pipelined: 2-buffer cross-tap prefetch (float4 loads, whole tap)
      constexpr int NQ4 = CLEN/4;
      float va[2][NPIX][NQ4][4];
      auto ldtap = [&](int kx, int buf){
#pragma unroll
        for (int t=0;t<NPIX;t++){
          int iy=iy0[t]+ky, ix=ix0[t]+kx;
          bool ok = pv[t] && iy>=0 && iy<H && ix>=0 && ix<W;
          const float* ip = base[t]+(size_t)(iy*W+ix)*CIN;
#pragma unroll
          for (int q=0;q<NQ4;q++)
            *(float4*)va[buf][t][q] = ok ? *(const float4*)(ip+q*4)
                                         : make_float4(0.f,0.f,0.f,0.f);
        }
      };
      ldtap(0,0);
#pragma unroll
      for (int kx=0; kx<KW; kx++){
        const int cur = kx&1;
        if (kx+1<KW) ldtap(kx+1, cur^1);
        const float* swt = swr + (size_t)kx*TAPF;
#pragma unroll
        for (int c=0;c<NQ4;c++){
          float wv[4][4];
#pragma unroll
          for (int r=0;r<4;r++)
            *(float4*)wv[r] = *(const float4*)(swt + (c*4+r)*COB + co);
#pragma unroll
          for (int t=0;t<NPIX;t++)
#pragma unroll
            for (int r=0;r<4;r++)
#pragma unroll
              for (int j=0;j<4;j++)
                acc[t][j]=fmaf(va[cur][t][c][r],wv[r][j],acc[t][j]);
        }
      }
    } else {
      // r8-exact general path (unroll 2 over ci quads)
      for (int kx=0; kx<KW; kx++){
        const float* swt = swr + (size_t)kx*TAPF;
        const float* ip[NPIX]; bool ok[NPIX];
#pragma unroll
        for (int t=0;t<NPIX;t++){
          int iy=iy0[t]+ky, ix=ix0[t]+kx;
          ok[t]=pv[t] && iy>=0 && iy<H && ix>=0 && ix<W;
          ip[t]=base[t]+(size_t)(iy*W+ix)*CIN;
        }
#pragma unroll 2
        for (int ci=0; ci<CLEN; ci+=4){
          float wv[4][4];
#pragma unroll
          for (int r=0;r<4;r++)
            *(float4*)wv[r] = *(const float4*)(swt + (ci+r)*COB + co);
#pragma unroll
          for (int t=0;t<NPIX;t++){
            float va[4];
            *(float4*)va = ok[t] ? *(const float4*)(ip[t]+ci)
                                 : make_float4(0.f,0.f,0.f,0.f);
#pragma unroll
            for (int r=0;r<4;r++)
#pragma unroll
              for (int j=0;j<4;j++)
                acc[t][j]=fmaf(va[r],wv[r][j],acc[t][j]);
          }
        }
      }
    }
  }

  float bv[4]={0.f,0.f,0.f,0.f};
  if constexpr (BIAS) *(float4*)bv = *(const float4*)(bias+gco);
#pragma unroll
  for (int t=0;t<NPIX;t++) if (pv[t]){
    float o[4];
#pragma unroll
    for (int j=0;j<4;j++){
      float v = acc[t][j]+bv[j];
      o[j] = ACT ? silu_f(v) : v;
    }
    *(float4*)(out + (size_t)(p0+t)*COUT + gco) = *(float4*)o;
  }
}

// ---------------------------------------------------------------------------
// reduce G partials (stride n) + bias + optional silu. (FROZEN)
// ---------------------------------------------------------------------------
template<int G,int COUT,bool ACT>
__global__ __launch_bounds__(256) void reduce_k(
    const float* __restrict__ p, const float* __restrict__ bias,
    float* __restrict__ out, int n)
{
  int i = (blockIdx.x*256+threadIdx.x)*4;
  if (i>=n) return;
  float a[4]; *(float4*)a = *(const float4*)(p+i);
#pragma unroll
  for (int g=1; g<G; g++){
    float b[4]; *(float4*)b = *(const float4*)(p+(size_t)g*n+i);
#pragma unroll
    for (int j=0;j<4;j++) a[j]+=b[j];
  }
  float bv[4]; *(float4*)bv = *(const float4*)(bias + (i % COUT));
#pragma unroll
  for (int j=0;j<4;j++){
    float v=a[j]+bv[j];
    a[j] = ACT ? silu_f(v) : v;
  }
  *(float4*)(out+i) = *(float4*)a;
}

// ---------------------------------------------------------------------------
// conv_transpose 5x5 s2 SAME (verified r0 mapping), per-tap LDS weight stage.
// parity = b&3, ci-group = (b>>2)&(G-1), spatial = b>>(2+GSH). r8-EXACT.
// ---------------------------------------------------------------------------
template<int CIN,int COUT,int NPIX,int G,bool DIRECT>
__global__ __launch_bounds__(256) void tconv_k(
    const float* __restrict__ in, const float* __restrict__ w,
    const float* __restrict__ bias, float* __restrict__ out,
    int N,int H,int W,int OH,int OW)
{
  constexpr int COQ  = COUT/4;
  constexpr int CLEN = CIN/G;
  constexpr int GSH  = LOG2<G>::v;
  constexpr int TAPF = CLEN*COUT;
  __shared__ float sw[TAPF];
  const int par = blockIdx.x & 3;
  const int py = par>>1, px = par&1;
  const int g  = (blockIdx.x>>2) & (G-1);
  const int bx = blockIdx.x >> (2+GSH);
  const int NKY = py?3:2, NKX = px?3:2;
  const int OHh=OH>>1, OWh=OW>>1;
  const int total = N*OHh*OWh;
  if (G>1) out += (size_t)g * N*OH*OW*COUT;

  int idx = bx*256 + (int)threadIdx.x;
  int cq = idx % COQ;
  int pg = idx / COQ;
  int co = cq*4;
  int p0 = pg*NPIX;

  float acc[NPIX][4] = {};
  int yy[NPIX], xx[NPIX], nn[NPIX]; const float* base[NPIX]; bool pv[NPIX];
#pragma unroll
  for (int t=0;t<NPIX;t++){
    int p=p0+t; pv[t]=(p<total); int pp=pv[t]?p:0;
    xx[t]=pp%OWh; int r=pp/OWh; yy[t]=r%OHh; nn[t]=r/OHh;
    base[t]=in+(size_t)nn[t]*H*W*CIN + g*CLEN;
  }

  for (int j=0;j<NKY;j++){
    int ky = 2*j + (py?0:1);
    for (int i=0;i<NKX;i++){
      int kx = 2*i + (px?0:1);
      __syncthreads();
      {
        constexpr int V = TAPF/4;
        const float4* src = (const float4*)(w + ((size_t)(ky*5+kx)*CIN + g*CLEN)*COUT);
        for (int v=threadIdx.x; v<V; v+=256) ((float4*)sw)[v]=src[v];
      }
      __syncthreads();
      const float* ip[NPIX]; bool ok[NPIX];
#pragma unroll
      for (int t=0;t<NPIX;t++){
        int iy=yy[t]+j-1, ix=xx[t]+i-1;
        ok[t]=pv[t] && iy>=0 && iy<H && ix>=0 && ix<W;
        ip[t]=base[t]+(size_t)(iy*W+ix)*CIN;
      }
#pragma unroll 2
      for (int ci=0; ci<CLEN; ci+=4){
        float wv[4][4];
#pragma unroll
        for (int r=0;r<4;r++)
          *(float4*)wv[r] = *(const float4*)(sw + (ci+r)*COUT + co);
#pragma unroll
        for (int t=0;t<NPIX;t++){
          float va[4];
          *(float4*)va = ok[t] ? *(const float4*)(ip[t]+ci)
                               : make_float4(0.f,0.f,0.f,0.f);
#pragma unroll
          for (int r=0;r<4;r++)
#pragma unroll
            for (int jj=0;jj<4;jj++)
              acc[t][jj]=fmaf(va[r],wv[r][jj],acc[t][jj]);
        }
      }
    }
  }

  float bv[4]={0.f,0.f,0.f,0.f};
  if constexpr (DIRECT) *(float4*)bv = *(const float4*)(bias+co);
#pragma unroll
  for (int t=0;t<NPIX;t++) if (pv[t]){
    float o[4];
#pragma unroll
    for (int jj=0;jj<4;jj++){
      float v = acc[t][jj]+bv[jj];
      o[jj] = DIRECT ? silu_f(v) : v;
    }
    *(float4*)(out + (((size_t)nn[t]*OH + (2*yy[t]+py))*OW + (2*xx[t]+px))*COUT + co) = *(float4*)o;
  }
}

// ---------------------------------------------------------------------------
// VQ fused with conv3c 2-partial reduction + bias (round-2 EXACT — FROZEN).
// ---------------------------------------------------------------------------
__global__ __launch_bounds__(256) void vq_k(
    const float* __restrict__ p, const float* __restrict__ bias,
    const float* __restrict__ cb, float* __restrict__ q, int NLat)
{
  __shared__ float slat[4][128];
  int wave = threadIdx.x >> 6;
  int lane = threadIdx.x & 63;
  int l = blockIdx.x*4 + wave;
  if (l >= NLat) return;
  const float* p0 = p + (size_t)l*128;
  const float* p1 = p0 + (size_t)NLat*128;
  slat[wave][lane]    = p0[lane]    + p1[lane]    + bias[lane];
  slat[wave][lane+64] = p0[lane+64] + p1[lane+64] + bias[lane+64];

  float bestd = INFINITY; int besti = 0;
  for (int c0=0;c0<256;c0+=64){
    int c = c0 + lane;
    const float* cp = cb + (size_t)c*128;
    float d = 0.f;
#pragma unroll 8
    for (int k=0;k<128;k+=4){
      float4 cv = *reinterpret_cast<const float4*>(cp+k);
      float d0 = slat[wave][k+0]-cv.x;
      float d1 = slat[wave][k+1]-cv.y;
      float d2 = slat[wave][k+2]-cv.z;
      float d3 = slat[wave][k+3]-cv.w;
      d += d0*d0; d += d1*d1; d += d2*d2; d += d3*d3;
    }
    if (d < bestd) { bestd = d; besti = c; }
  }
  for (int off=32; off; off>>=1){
    float od = __shfl_down(bestd, off);
    int   oi = __shfl_down(besti, off);
    if (od < bestd || (od == bestd && oi < besti)) { bestd=od; besti=oi; }
  }
  besti = __shfl(besti, 0);
  const float* cp = cb + (size_t)besti*128;
  float* qp = q + (size_t)l*128;
  qp[lane]    = cp[lane];
  qp[lane+64] = cp[lane+64];
}

// ---------------------------------------------------------------------------
// Final 3x3 conv 32->3 split over ky rows (g = blockIdx%3). Writes partials.
// ---------------------------------------------------------------------------
__global__ __launch_bounds__(256) void conv_last_k(
    const float* __restrict__ in, const float* __restrict__ w,
    float* __restrict__ p, int N,int H,int W)
{
  int g = blockIdx.x % 3;
  int bx = blockIdx.x / 3;
  int pix = bx*256 + threadIdx.x;
  int total = N*H*W;
  if (pix>=total) return;
  int x = pix % W; int r = pix / W; int y = r % H; int n = r / H;
  float a0=0.f, a1=0.f, a2=0.f;
  int iy = y + g - 1;
  if (iy>=0 && iy<H){
    const float* base = in + ((size_t)n*H + iy)*W*32;
    for (int kx=0;kx<3;kx++){
      int ix=x+kx-1; if(ix<0||ix>=W) continue;
      const float* ip = base + (size_t)ix*32;
      const float* wp = w + (size_t)((g*3+kx)*32)*3;
#pragma unroll
      for (int ci=0;ci<32;ci+=4){
        float va[4]; *(float4*)va = *(const float4*)(ip+ci);
        float wv[12];
        *(float4*)(wv+0) = *(const float4*)(wp+ci*3+0);
        *(float4*)(wv+4) = *(const float4*)(wp+ci*3+4);
        *(float4*)(wv+8) = *(const float4*)(wp+ci*3+8);
#pragma unroll
        for (int r2=0;r2<4;r2++){
          a0 = fmaf(va[r2], wv[r2*3+0], a0);
          a1 = fmaf(va[r2], wv[r2*3+1], a1);
          a2 = fmaf(va[r2], wv[r2*3+2], a2);
        }
      }
    }
  }
  float* pp = p + (size_t)g*total*3 + (size_t)pix*3;
  pp[0]=a0; pp[1]=a1; pp[2]=a2;
}

__global__ __launch_bounds__(256) void reduce_last_k(
    const float* __restrict__ p, const float* __restrict__ bias,
    float* __restrict__ out, int n)
{
  int i = (blockIdx.x*256+threadIdx.x)*4;
  if (i>=n) return;
  float a[4]; *(float4*)a = *(const float4*)(p+i);
#pragma unroll
  for (int g=1; g<3; g++){
    float b[4]; *(float4*)b = *(const float4*)(p+(size_t)g*n+i);
#pragma unroll
    for (int j=0;j<4;j++) a[j]+=b[j];
  }
  float o[4];
#pragma unroll
  for (int j=0;j<4;j++) o[j] = a[j] + bias[(i+j)%3];
  *(float4*)(out+i) = *(float4*)o;
}

extern "C" void kernel_launch(void* const* d_in, const int* in_sizes, int n_in,
                              void* d_out, int out_size, void* d_ws, size_t ws_size,
                              hipStream_t stream) {
  const float* x    = (const float*)d_in[0];
  const float* k1   = (const float*)d_in[1];  const float* b1  = (const float*)d_in[2];
  const float* k1c  = (const float*)d_in[3];  const float* b1c = (const float*)d_in[4];
  const float* k2   = (const float*)d_in[5];  const float* b2  = (const float*)d_in[6];
  const float* k2c  = (const float*)d_in[7];  const float* b2c = (const float*)d_in[8];
  const float* k3   = (const float*)d_in[9];  const float* b3  = (const float*)d_in[10];
  const float* k3c  = (const float*)d_in[11]; const float* b3c = (const float*)d_in[12];
  const float* cb   = (const float*)d_in[13];
  const float* tk1  = (const float*)d_in[14]; const float* tb1  = (const float*)d_in[15];
  const float* tk1c = (const float*)d_in[16]; const float* tb1c = (const float*)d_in[17];
  const float* tk2  = (const float*)d_in[18]; const float* tb2  = (const float*)d_in[19];
  const float* tk2c = (const float*)d_in[20]; const float* tb2c = (const float*)d_in[21];
  const float* tk3  = (const float*)d_in[22]; const float* tb3  = (const float*)d_in[23];
  const float* tk3c = (const float*)d_in[24]; const float* tb3c = (const float*)d_in[25];
  float* out = (float*)d_out;

  float* S  = (float*)d_ws;
  float* W0 = S;                 // [0 .. 1M) floats
  float* W1 = S + 1048576;       // [1M .. 2M)
  float* P  = S + 2097152;       // [2M .. 6M)
  dim3 blk(256);

  // ---- r8-EXACT grids/configs; only CLEN<=16 inner loops pipelined ----
  conv_k<11,11,2,4,  3, 32,1,true ,true ,1,2><<<1024,blk,0,stream>>>(x,  k1,  b1,  W0, 8,128,128,64,64);
  conv_k< 3, 3,1,1, 32, 32,1,true ,true ,1,2><<<1024,blk,0,stream>>>(W0, k1c, b1c, W1, 8,64,64,64,64);
  conv_k<11,11,2,4, 32, 64,1,false,false,2,2><<<1024,blk,0,stream>>>(W1, k2,  nullptr, P, 8,64,64,32,32);
  reduce_k<2, 64,true><<< 512,blk,0,stream>>>(P, b2,  W0, 524288);
  conv_k< 3, 3,1,1, 64, 64,1,true ,true ,1,2><<< 512,blk,0,stream>>>(W0, k2c, b2c, W1, 8,32,32,32,32);
  conv_k<11,11,2,4, 64,128,1,false,false,4,4><<<1024,blk,0,stream>>>(W1, k3,  nullptr, P, 8,32,32,16,16);
  reduce_k<4,128,true><<< 256,blk,0,stream>>>(P, b3,  W0, 262144);
  conv_k< 3, 3,1,1,128,128,1,false,false,2,4><<< 512,blk,0,stream>>>(W0, k3c, nullptr, P, 8,16,16,16,16);
  // ---- VQ: r2-exact 2-partial reduce + argmin + gather (FROZEN) ----
  vq_k<<<512,blk,0,stream>>>(P, b3c, cb, W1, 2048);
  // ---- decoder (r8-exact) ----
  tconv_k<128,64,1,4,false><<<2048,blk,0,stream>>>(W1, tk1, nullptr, P, 8,16,16,32,32);
  reduce_k<4, 64,true><<< 512,blk,0,stream>>>(P, tb1,  W0, 524288);
  conv_k< 3, 3,1,1, 64, 64,1,false,false,2,2><<<1024,blk,0,stream>>>(W0, tk1c, nullptr, P, 8,32,32,32,32);
  reduce_k<2, 64,true><<< 512,blk,0,stream>>>(P, tb1c, W1, 524288);
  tconv_k< 64,32,1,2,false><<<2048,blk,0,stream>>>(W1, tk2, nullptr, P, 8,32,32,64,64);
  reduce_k<2, 32,true><<<1024,blk,0,stream>>>(P, tb2,  W0, 1048576);
  conv_k< 3, 3,1,1, 32, 32,1,true ,true ,1,2><<<1024,blk,0,stream>>>(W0, tk2c, tb2c, W1, 8,64,64,64,64);
  tconv_k< 32,32,2,1,true ><<<2048,blk,0,stream>>>(W1, tk3, tb3, P, 8,64,64,128,128);
  conv_last_k<<<1536,blk,0,stream>>>(P, tk3c, S, 8,128,128);
  reduce_last_k<<<384,blk,0,stream>>>(S, tb3c, out, 393216);
}

// Round 14
// 525.883 us; speedup vs baseline: 8.2028x; 8.2028x over previous
//
#include <hip/hip_runtime.h>

#define DI __device__ __forceinline__
DI float silu_f(float x){ return x * (1.0f/(1.0f+__expf(-x))); }

template<int X> struct LOG2 { static constexpr int v = 1 + LOG2<X/2>::v; };
template<> struct LOG2<1> { static constexpr int v = 0; };

// ---------------------------------------------------------------------------
// Direct conv, NHWC in, HWIO weights, LDS-staged weight slices (r8 config).
// Thread = NPIX pixels x 4 co. G: ci-split (FROZEN — VQ argmin is sensitive
// to latent rounding). CS: co-split across blocks (numerics-free).
// r14: TOW>0 path (conv2/conv3): block = whole output row(s); per ky, stage
// the input row band into LDS once (padding resolved at staging) -> tap loop
// is pure LDS (weights broadcast; input at 32B stride = 2-way aliasing,
// free per m136), no bounds VALU, 4.6x less global input traffic. Values and
// per-output fmaf order (ky->kx->ci asc->r asc) UNCHANGED -> bit-identical.
// r9/r13 lesson: NO register-level prefetch (compiler hoists -> 256 VGPR
// spill). TOW=0 path is r8-EXACT.
// ---------------------------------------------------------------------------
template<int KH,int KW,int STRIDE,int PAD,int CIN,int COUT,int NPIX,
         bool ACT,bool BIAS,int G,int CS,int TOW>
__global__ __launch_bounds__(256) void conv_k(
    const float* __restrict__ in, const float* __restrict__ w,
    const float* __restrict__ bias, float* __restrict__ out,
    int N,int H,int W,int OH,int OW)
{
  constexpr int CLEN = CIN/G;
  constexpr int COB  = COUT/CS;
  constexpr int COQ  = COB/4;
  constexpr int GSH  = LOG2<G>::v;
  constexpr int CSH  = LOG2<CS>::v;
  constexpr int TAPF = CLEN*COB;
  constexpr bool SALL = (KH*KW*TAPF*4) <= 47*1024;
  constexpr int NTAP = SALL ? KH*KW : KW;
  static_assert(CLEN==3 || (CLEN%4)==0, "ci");
  static_assert(TOW==0 || (!SALL && NPIX==1), "tow");
  __shared__ float sw[NTAP*TAPF];
  // input row-band staging (TOW>0 only)
  constexpr int SPAN = (TOW>0) ? (TOW-1)*STRIDE + KW : 1;
  constexpr int ROWS = (TOW>0) ? (256/COQ)/TOW : 1;
  constexpr int CQ4  = (TOW>0) ? CLEN/4 : 1;
  __shared__ float si[(TOW>0) ? ROWS*CQ4*SPAN*4 : 1];

  const int g  = blockIdx.x & (G-1);
  const int cs = (blockIdx.x >> GSH) & (CS-1);
  const int bx = blockIdx.x >> (GSH+CSH);
  const int total = N*OH*OW;
  if (G>1) out += (size_t)g * total * COUT;
  const int ci_off  = g*CLEN;
  const int co_base = cs*COB;

  int idx = bx*256 + (int)threadIdx.x;
  int cq = idx % COQ;
  int pg = idx / COQ;
  int co = cq*4;                 // within block's co slice
  int gco = co_base + co;        // global co
  int p0 = pg*NPIX;

  float acc[NPIX][4] = {};
  int iy0[NPIX], ix0[NPIX]; const float* base[NPIX]; bool pv[NPIX];
#pragma unroll
  for (int t=0;t<NPIX;t++){
    int p=p0+t; pv[t]=(p<total); int pp=pv[t]?p:0;
    int ox=pp%OW; int r=pp/OW; int oy=r%OH; int n=r/OH;
    iy0[t]=oy*STRIDE-PAD; ix0[t]=ox*STRIDE-PAD;
    base[t]=in+(size_t)n*H*W*CIN + ci_off;
  }

  auto stage = [&](int tap0){
    constexpr int TQ = TAPF/4;
    constexpr int V  = NTAP*TQ;
    for (int v=threadIdx.x; v<V; v+=256){
      int tap = v / TQ; int rem = v - tap*TQ;
      float4 q;
      if constexpr (CS==1){
        const float4* src = (const float4*)(w + ((size_t)(tap0+tap)*CIN + ci_off)*COUT);
        q = src[rem];
      } else {
        int ci = rem / (COB/4); int r2 = rem - ci*(COB/4);
        q = *(const float4*)(w + ((size_t)(tap0+tap)*CIN + ci_off + ci)*COUT
                               + co_base + r2*4);
      }
      *(float4*)(sw + (size_t)tap*TAPF + rem*4) = q;
    }
  };

  if constexpr (SALL){
    stage(0);
    __syncthreads();
  }

  if constexpr (TOW>0){
    // ---- row-band LDS path (conv2/conv3) ----
    const int pb0 = bx * (256/COQ);      // first pixel of this block
    const int r0  = pb0 / TOW;           // first output row index (global)
    const int oy0 = r0 % OH;
    const int n0  = r0 / OH;             // ROWS rows never cross n (OH%ROWS==0)
    const int myrow = (p0 - pb0) / TOW;
    const int oxl   = (p0 - pb0) - myrow*TOW;

    for (int ky=0; ky<KH; ky++){
      __syncthreads();
      stage(ky*KW);
      {
        constexpr int INQ = ROWS*CQ4*SPAN;
        for (int v=(int)threadIdx.x; v<INQ; v+=256){
          int r  = v / (CQ4*SPAN);
          int rm = v - r*(CQ4*SPAN);
          int q  = rm / SPAN;
          int ixo= rm - q*SPAN;
          int iy = (oy0+r)*STRIDE - PAD + ky;
          int ix = ixo - PAD;
          bool ok = iy>=0 && iy<H && ix>=0 && ix<W;
          float4 val = ok ? *(const float4*)(in + ((size_t)(n0*H+iy)*W + ix)*CIN + ci_off + q*4)
                          : make_float4(0.f,0.f,0.f,0.f);
          *(float4*)&si[(size_t)v*4] = val;
        }
      }
      __syncthreads();
      const float* swr = sw;
      for (int kx=0; kx<KW; kx++){
        const float* swt = swr + (size_t)kx*TAPF;
        const int ib = oxl*STRIDE + kx;
#pragma unroll 2
        for (int c=0; c<CQ4; c++){
          float wv[4][4];
#pragma unroll
          for (int r=0;r<4;r++)
            *(float4*)wv[r] = *(const float4*)(swt + (c*4+r)*COB + co);
          float va[4];
          *(float4*)va = *(const float4*)&si[(size_t)((myrow*CQ4 + c)*SPAN + ib)*4];
#pragma unroll
          for (int r=0;r<4;r++)
#pragma unroll
            for (int j=0;j<4;j++)
              acc[0][j]=fmaf(va[r],wv[r][j],acc[0][j]);
        }
      }
    }
  } else {
    // ---- r8-EXACT path ----
    for (int ky=0; ky<KH; ky++){
      if constexpr (!SALL){
        __syncthreads();
        stage(ky*KW);
        __syncthreads();
      }
      const float* swr = SALL ? sw + (size_t)ky*KW*TAPF : sw;
      for (int kx=0; kx<KW; kx++){
        const float* swt = swr + (size_t)kx*TAPF;
        const float* ip[NPIX]; bool ok[NPIX];
#pragma unroll
        for (int t=0;t<NPIX;t++){
          int iy=iy0[t]+ky, ix=ix0[t]+kx;
          ok[t]=pv[t] && iy>=0 && iy<H && ix>=0 && ix<W;
          ip[t]=base[t]+(size_t)(iy*W+ix)*CIN;
        }
        if constexpr (CLEN==3){
          float wv[3][4];
          *(float4*)wv[0]=*(const float4*)(swt + 0*COB + co);
          *(float4*)wv[1]=*(const float4*)(swt + 1*COB + co);
          *(float4*)wv[2]=*(const float4*)(swt + 2*COB + co);
#pragma unroll
          for (int t=0;t<NPIX;t++){
            float v0=ok[t]?ip[t][0]:0.f;
            float v1=ok[t]?ip[t][1]:0.f;
            float v2=ok[t]?ip[t][2]:0.f;
#pragma unroll
            for (int j=0;j<4;j++)
              acc[t][j]=fmaf(v0,wv[0][j],fmaf(v1,wv[1][j],fmaf(v2,wv[2][j],acc[t][j])));
          }
        } else {
#pragma unroll 2
          for (int ci=0; ci<CLEN; ci+=4){
            float wv[4][4];
#pragma unroll
            for (int r=0;r<4;r++)
              *(float4*)wv[r] = *(const float4*)(swt + (ci+r)*COB + co);
#pragma unroll
            for (int t=0;t<NPIX;t++){
              float va[4];
              *(float4*)va = ok[t] ? *(const float4*)(ip[t]+ci)
                                   : make_float4(0.f,0.f,0.f,0.f);
#pragma unroll
              for (int r=0;r<4;r++)
#pragma unroll
                for (int j=0;j<4;j++)
                  acc[t][j]=fmaf(va[r],wv[r][j],acc[t][j]);
            }
          }
        }
      }
    }
  }

  float bv[4]={0.f,0.f,0.f,0.f};
  if constexpr (BIAS) *(float4*)bv = *(const float4*)(bias+gco);
#pragma unroll
  for (int t=0;t<NPIX;t++) if (pv[t]){
    float o[4];
#pragma unroll
    for (int j=0;j<4;j++){
      float v = acc[t][j]+bv[j];
      o[j] = ACT ? silu_f(v) : v;
    }
    *(float4*)(out + (size_t)(p0+t)*COUT + gco) = *(float4*)o;
  }
}

// ---------------------------------------------------------------------------
// reduce G partials (stride n) + bias + optional silu. (FROZEN)
// ---------------------------------------------------------------------------
template<int G,int COUT,bool ACT>
__global__ __launch_bounds__(256) void reduce_k(
    const float* __restrict__ p, const float* __restrict__ bias,
    float* __restrict__ out, int n)
{
  int i = (blockIdx.x*256+threadIdx.x)*4;
  if (i>=n) return;
  float a[4]; *(float4*)a = *(const float4*)(p+i);
#pragma unroll
  for (int g=1; g<G; g++){
    float b[4]; *(float4*)b = *(const float4*)(p+(size_t)g*n+i);
#pragma unroll
    for (int j=0;j<4;j++) a[j]+=b[j];
  }
  float bv[4]; *(float4*)bv = *(const float4*)(bias + (i % COUT));
#pragma unroll
  for (int j=0;j<4;j++){
    float v=a[j]+bv[j];
    a[j] = ACT ? silu_f(v) : v;
  }
  *(float4*)(out+i) = *(float4*)a;
}

// ---------------------------------------------------------------------------
// conv_transpose 5x5 s2 SAME (verified r0 mapping), per-tap LDS weight stage.
// parity = b&3, ci-group = (b>>2)&(G-1), spatial = b>>(2+GSH). r8-EXACT.
// ---------------------------------------------------------------------------
template<int CIN,int COUT,int NPIX,int G,bool DIRECT>
__global__ __launch_bounds__(256) void tconv_k(
    const float* __restrict__ in, const float* __restrict__ w,
    const float* __restrict__ bias, float* __restrict__ out,
    int N,int H,int W,int OH,int OW)
{
  constexpr int COQ  = COUT/4;
  constexpr int CLEN = CIN/G;
  constexpr int GSH  = LOG2<G>::v;
  constexpr int TAPF = CLEN*COUT;
  __shared__ float sw[TAPF];
  const int par = blockIdx.x & 3;
  const int py = par>>1, px = par&1;
  const int g  = (blockIdx.x>>2) & (G-1);
  const int bx = blockIdx.x >> (2+GSH);
  const int NKY = py?3:2, NKX = px?3:2;
  const int OHh=OH>>1, OWh=OW>>1;
  const int total = N*OHh*OWh;
  if (G>1) out += (size_t)g * N*OH*OW*COUT;

  int idx = bx*256 + (int)threadIdx.x;
  int cq = idx % COQ;
  int pg = idx / COQ;
  int co = cq*4;
  int p0 = pg*NPIX;

  float acc[NPIX][4] = {};
  int yy[NPIX], xx[NPIX], nn[NPIX]; const float* base[NPIX]; bool pv[NPIX];
#pragma unroll
  for (int t=0;t<NPIX;t++){
    int p=p0+t; pv[t]=(p<total); int pp=pv[t]?p:0;
    xx[t]=pp%OWh; int r=pp/OWh; yy[t]=r%OHh; nn[t]=r/OHh;
    base[t]=in+(size_t)nn[t]*H*W*CIN + g*CLEN;
  }

  for (int j=0;j<NKY;j++){
    int ky = 2*j + (py?0:1);
    for (int i=0;i<NKX;i++){
      int kx = 2*i + (px?0:1);
      __syncthreads();
      {
        constexpr int V = TAPF/4;
        const float4* src = (const float4*)(w + ((size_t)(ky*5+kx)*CIN + g*CLEN)*COUT);
        for (int v=threadIdx.x; v<V; v+=256) ((float4*)sw)[v]=src[v];
      }
      __syncthreads();
      const float* ip[NPIX]; bool ok[NPIX];
#pragma unroll
      for (int t=0;t<NPIX;t++){
        int iy=yy[t]+j-1, ix=xx[t]+i-1;
        ok[t]=pv[t] && iy>=0 && iy<H && ix>=0 && ix<W;
        ip[t]=base[t]+(size_t)(iy*W+ix)*CIN;
      }
#pragma unroll 2
      for (int ci=0; ci<CLEN; ci+=4){
        float wv[4][4];
#pragma unroll
        for (int r=0;r<4;r++)
          *(float4*)wv[r] = *(const float4*)(sw + (ci+r)*COUT + co);
#pragma unroll
        for (int t=0;t<NPIX;t++){
          float va[4];
          *(float4*)va = ok[t] ? *(const float4*)(ip[t]+ci)
                               : make_float4(0.f,0.f,0.f,0.f);
#pragma unroll
          for (int r=0;r<4;r++)
#pragma unroll
            for (int jj=0;jj<4;jj++)
              acc[t][jj]=fmaf(va[r],wv[r][jj],acc[t][jj]);
        }
      }
    }
  }

  float bv[4]={0.f,0.f,0.f,0.f};
  if constexpr (DIRECT) *(float4*)bv = *(const float4*)(bias+co);
#pragma unroll
  for (int t=0;t<NPIX;t++) if (pv[t]){
    float o[4];
#pragma unroll
    for (int jj=0;jj<4;jj++){
      float v = acc[t][jj]+bv[jj];
      o[jj] = DIRECT ? silu_f(v) : v;
    }
    *(float4*)(out + (((size_t)nn[t]*OH + (2*yy[t]+py))*OW + (2*xx[t]+px))*COUT + co) = *(float4*)o;
  }
}

// ---------------------------------------------------------------------------
// VQ fused with conv3c 2-partial reduction + bias (round-2 EXACT — FROZEN).
// ---------------------------------------------------------------------------
__global__ __launch_bounds__(256) void vq_k(
    const float* __restrict__ p, const float* __restrict__ bias,
    const float* __restrict__ cb, float* __restrict__ q, int NLat)
{
  __shared__ float slat[4][128];
  int wave = threadIdx.x >> 6;
  int lane = threadIdx.x & 63;
  int l = blockIdx.x*4 + wave;
  if (l >= NLat) return;
  const float* p0 = p + (size_t)l*128;
  const float* p1 = p0 + (size_t)NLat*128;
  slat[wave][lane]    = p0[lane]    + p1[lane]    + bias[lane];
  slat[wave][lane+64] = p0[lane+64] + p1[lane+64] + bias[lane+64];

  float bestd = INFINITY; int besti = 0;
  for (int c0=0;c0<256;c0+=64){
    int c = c0 + lane;
    const float* cp = cb + (size_t)c*128;
    float d = 0.f;
#pragma unroll 8
    for (int k=0;k<128;k+=4){
      float4 cv = *reinterpret_cast<const float4*>(cp+k);
      float d0 = slat[wave][k+0]-cv.x;
      float d1 = slat[wave][k+1]-cv.y;
      float d2 = slat[wave][k+2]-cv.z;
      float d3 = slat[wave][k+3]-cv.w;
      d += d0*d0; d += d1*d1; d += d2*d2; d += d3*d3;
    }
    if (d < bestd) { bestd = d; besti = c; }
  }
  for (int off=32; off; off>>=1){
    float od = __shfl_down(bestd, off);
    int   oi = __shfl_down(besti, off);
    if (od < bestd || (od == bestd && oi < besti)) { bestd=od; besti=oi; }
  }
  besti = __shfl(besti, 0);
  const float* cp = cb + (size_t)besti*128;
  float* qp = q + (size_t)l*128;
  qp[lane]    = cp[lane];
  qp[lane+64] = cp[lane+64];
}

// ---------------------------------------------------------------------------
// Final 3x3 conv 32->3 split over ky rows (g = blockIdx%3). Writes partials.
// ---------------------------------------------------------------------------
__global__ __launch_bounds__(256) void conv_last_k(
    const float* __restrict__ in, const float* __restrict__ w,
    float* __restrict__ p, int N,int H,int W)
{
  int g = blockIdx.x % 3;
  int bx = blockIdx.x / 3;
  int pix = bx*256 + threadIdx.x;
  int total = N*H*W;
  if (pix>=total) return;
  int x = pix % W; int r = pix / W; int y = r % H; int n = r / H;
  float a0=0.f, a1=0.f, a2=0.f;
  int iy = y + g - 1;
  if (iy>=0 && iy<H){
    const float* base = in + ((size_t)n*H + iy)*W*32;
    for (int kx=0;kx<3;kx++){
      int ix=x+kx-1; if(ix<0||ix>=W) continue;
      const float* ip = base + (size_t)ix*32;
      const float* wp = w + (size_t)((g*3+kx)*32)*3;
#pragma unroll
      for (int ci=0;ci<32;ci+=4){
        float va[4]; *(float4*)va = *(const float4*)(ip+ci);
        float wv[12];
        *(float4*)(wv+0) = *(const float4*)(wp+ci*3+0);
        *(float4*)(wv+4) = *(const float4*)(wp+ci*3+4);
        *(float4*)(wv+8) = *(const float4*)(wp+ci*3+8);
#pragma unroll
        for (int r2=0;r2<4;r2++){
          a0 = fmaf(va[r2], wv[r2*3+0], a0);
          a1 = fmaf(va[r2], wv[r2*3+1], a1);
          a2 = fmaf(va[r2], wv[r2*3+2], a2);
        }
      }
    }
  }
  float* pp = p + (size_t)g*total*3 + (size_t)pix*3;
  pp[0]=a0; pp[1]=a1; pp[2]=a2;
}

__global__ __launch_bounds__(256) void reduce_last_k(
    const float* __restrict__ p, const float* __restrict__ bias,
    float* __restrict__ out, int n)
{
  int i = (blockIdx.x*256+threadIdx.x)*4;
  if (i>=n) return;
  float a[4]; *(float4*)a = *(const float4*)(p+i);
#pragma unroll
  for (int g=1; g<3; g++){
    float b[4]; *(float4*)b = *(const float4*)(p+(size_t)g*n+i);
#pragma unroll
    for (int j=0;j<4;j++) a[j]+=b[j];
  }
  float o[4];
#pragma unroll
  for (int j=0;j<4;j++) o[j] = a[j] + bias[(i+j)%3];
  *(float4*)(out+i) = *(float4*)o;
}

extern "C" void kernel_launch(void* const* d_in, const int* in_sizes, int n_in,
                              void* d_out, int out_size, void* d_ws, size_t ws_size,
                              hipStream_t stream) {
  const float* x    = (const float*)d_in[0];
  const float* k1   = (const float*)d_in[1];  const float* b1  = (const float*)d_in[2];
  const float* k1c  = (const float*)d_in[3];  const float* b1c = (const float*)d_in[4];
  const float* k2   = (const float*)d_in[5];  const float* b2  = (const float*)d_in[6];
  const float* k2c  = (const float*)d_in[7];  const float* b2c = (const float*)d_in[8];
  const float* k3   = (const float*)d_in[9];  const float* b3  = (const float*)d_in[10];
  const float* k3c  = (const float*)d_in[11]; const float* b3c = (const float*)d_in[12];
  const float* cb   = (const float*)d_in[13];
  const float* tk1  = (const float*)d_in[14]; const float* tb1  = (const float*)d_in[15];
  const float* tk1c = (const float*)d_in[16]; const float* tb1c = (const float*)d_in[17];
  const float* tk2  = (const float*)d_in[18]; const float* tb2  = (const float*)d_in[19];
  const float* tk2c = (const float*)d_in[20]; const float* tb2c = (const float*)d_in[21];
  const float* tk3  = (const float*)d_in[22]; const float* tb3  = (const float*)d_in[23];
  const float* tk3c = (const float*)d_in[24]; const float* tb3c = (const float*)d_in[25];
  float* out = (float*)d_out;

  float* S  = (float*)d_ws;
  float* W0 = S;                 // [0 .. 1M) floats
  float* W1 = S + 1048576;       // [1M .. 2M)
  float* P  = S + 2097152;       // [2M .. 6M)
  dim3 blk(256);

  // ---- r8-EXACT grids/configs; TOW row-band LDS on conv2/conv3 only ----
  conv_k<11,11,2,4,  3, 32,1,true ,true ,1,2, 0><<<1024,blk,0,stream>>>(x,  k1,  b1,  W0, 8,128,128,64,64);
  conv_k< 3, 3,1,1, 32, 32,1,true ,true ,1,2, 0><<<1024,blk,0,stream>>>(W0, k1c, b1c, W1, 8,64,64,64,64);
  // conv2: block = one output row (OW=32) x 32 co; row-band LDS (27.2KB)
  conv_k<11,11,2,4, 32, 64,1,false,false,2,2,32><<<1024,blk,0,stream>>>(W1, k2,  nullptr, P, 8,64,64,32,32);
  reduce_k<2, 64,true><<< 512,blk,0,stream>>>(P, b2,  W0, 524288);
  conv_k< 3, 3,1,1, 64, 64,1,true ,true ,1,2, 0><<< 512,blk,0,stream>>>(W0, k2c, b2c, W1, 8,32,32,32,32);
  // conv3: block = two output rows (OW=16) x 32 co; row-band LDS (27.8KB)
  conv_k<11,11,2,4, 64,128,1,false,false,4,4,16><<<1024,blk,0,stream>>>(W1, k3,  nullptr, P, 8,32,32,16,16);
  reduce_k<4,128,true><<< 256,blk,0,stream>>>(P, b3,  W0, 262144);
  conv_k< 3, 3,1,1,128,128,1,false,false,2,4, 0><<< 512,blk,0,stream>>>(W0, k3c, nullptr, P, 8,16,16,16,16);
  // ---- VQ: r2-exact 2-partial reduce + argmin + gather (FROZEN) ----
  vq_k<<<512,blk,0,stream>>>(P, b3c, cb, W1, 2048);
  // ---- decoder (r8-exact) ----
  tconv_k<128,64,1,4,false><<<2048,blk,0,stream>>>(W1, tk1, nullptr, P, 8,16,16,32,32);
  reduce_k<4, 64,true><<< 512,blk,0,stream>>>(P, tb1,  W0, 524288);
  conv_k< 3, 3,1,1, 64, 64,1,false,false,2,2, 0><<<1024,blk,0,stream>>>(W0, tk1c, nullptr, P, 8,32,32,32,32);
  reduce_k<2, 64,true><<< 512,blk,0,stream>>>(P, tb1c, W1, 524288);
  tconv_k< 64,32,1,2,false><<<2048,blk,0,stream>>>(W1, tk2, nullptr, P, 8,32,32,64,64);
  reduce_k<2, 32,true><<<1024,blk,0,stream>>>(P, tb2,  W0, 1048576);
  conv_k< 3, 3,1,1, 32, 32,1,true ,true ,1,2, 0><<<1024,blk,0,stream>>>(W0, tk2c, tb2c, W1, 8,64,64,64,64);
  tconv_k< 32,32,2,1,true ><<<2048,blk,0,stream>>>(W1, tk3, tb3, P, 8,64,64,128,128);
  conv_last_k<<<1536,blk,0,stream>>>(P, tk3c, S, 8,128,128);
  reduce_last_k<<<384,blk,0,stream>>>(S, tb3c, out, 393216);
}

// Round 15
// 496.674 us; speedup vs baseline: 8.6852x; 1.0588x over previous
//
#include <hip/hip_runtime.h>

#define DI __device__ __forceinline__
DI float silu_f(float x){ return x * (1.0f/(1.0f+__expf(-x))); }

template<int X> struct LOG2 { static constexpr int v = 1 + LOG2<X/2>::v; };
template<> struct LOG2<1> { static constexpr int v = 0; };

// ---------------------------------------------------------------------------
// Direct conv, NHWC in, HWIO weights, LDS-staged weight slices.
// Thread = NPIX pixels x 4 co. G: ci-split (FROZEN — VQ argmin is sensitive
// to latent rounding). CS: co-split across blocks (numerics-free).
// TOW>0 (r14-proven, bit-identical): block = whole output row(s); per ky,
// stage the input row band into LDS once (padding resolved at staging) ->
// tap loop is pure LDS, no bounds VALU, ~5x less global input traffic.
// r15: TOW generalized to SALL weights (stage once) + CLEN==3 (scalar si);
// applied to conv1/conv1c/conv2c/conv3c/tk1c/tk2c as well.
// r9/r13 lesson: NO register-level prefetch (compiler hoists -> spills).
// Per-output fmaf chain order (ky->kx->ci asc->r asc) UNCHANGED everywhere.
// ---------------------------------------------------------------------------
template<int KH,int KW,int STRIDE,int PAD,int CIN,int COUT,int NPIX,
         bool ACT,bool BIAS,int G,int CS,int TOW>
__global__ __launch_bounds__(256) void conv_k(
    const float* __restrict__ in, const float* __restrict__ w,
    const float* __restrict__ bias, float* __restrict__ out,
    int N,int H,int W,int OH,int OW)
{
  constexpr int CLEN = CIN/G;
  constexpr int COB  = COUT/CS;
  constexpr int COQ  = COB/4;
  constexpr int GSH  = LOG2<G>::v;
  constexpr int CSH  = LOG2<CS>::v;
  constexpr int TAPF = CLEN*COB;
  constexpr bool SALL = (KH*KW*TAPF*4) <= 47*1024;
  constexpr int NTAP = SALL ? KH*KW : KW;
  static_assert(CLEN==3 || (CLEN%4)==0, "ci");
  static_assert(TOW==0 || NPIX==1, "tow");
  __shared__ float sw[NTAP*TAPF];
  // input row-band staging (TOW>0 only)
  constexpr int SPAN = (TOW>0) ? (TOW-1)*STRIDE + KW : 1;
  constexpr int ROWS = (TOW>0) ? (256/COQ)/TOW : 1;
  constexpr int CQ4  = (TOW>0 && CLEN!=3) ? CLEN/4 : 1;
  constexpr int SI_F = (TOW==0) ? 1 : (CLEN==3 ? ROWS*SPAN*3 : ROWS*CQ4*SPAN*4);
  __shared__ float si[SI_F];

  const int g  = blockIdx.x & (G-1);
  const int cs = (blockIdx.x >> GSH) & (CS-1);
  const int bx = blockIdx.x >> (GSH+CSH);
  const int total = N*OH*OW;
  if (G>1) out += (size_t)g * total * COUT;
  const int ci_off  = g*CLEN;
  const int co_base = cs*COB;

  int idx = bx*256 + (int)threadIdx.x;
  int cq = idx % COQ;
  int pg = idx / COQ;
  int co = cq*4;                 // within block's co slice
  int gco = co_base + co;        // global co
  int p0 = pg*NPIX;

  float acc[NPIX][4] = {};
  int iy0[NPIX], ix0[NPIX]; const float* base[NPIX]; bool pv[NPIX];
#pragma unroll
  for (int t=0;t<NPIX;t++){
    int p=p0+t; pv[t]=(p<total); int pp=pv[t]?p:0;
    int ox=pp%OW; int r=pp/OW; int oy=r%OH; int n=r/OH;
    iy0[t]=oy*STRIDE-PAD; ix0[t]=ox*STRIDE-PAD;
    base[t]=in+(size_t)n*H*W*CIN + ci_off;
  }

  auto stage = [&](int tap0){
    constexpr int TQ = (CLEN==3) ? (TAPF/4) : (TAPF/4);
    constexpr int V  = NTAP*TQ;
    for (int v=threadIdx.x; v<V; v+=256){
      int tap = v / TQ; int rem = v - tap*TQ;
      float4 q;
      if constexpr (CS==1){
        const float4* src = (const float4*)(w + ((size_t)(tap0+tap)*CIN + ci_off)*COUT);
        q = src[rem];
      } else if constexpr (CLEN==3){
        // 3 ci rows x COB; quads within tap slice (COB%4==0, TAPF=3*COB)
        int ci = rem / (COB/4); int r2 = rem - ci*(COB/4);
        q = *(const float4*)(w + ((size_t)(tap0+tap)*CIN + ci)*COUT
                               + co_base + r2*4);
      } else {
        int ci = rem / (COB/4); int r2 = rem - ci*(COB/4);
        q = *(const float4*)(w + ((size_t)(tap0+tap)*CIN + ci_off + ci)*COUT
                               + co_base + r2*4);
      }
      *(float4*)(sw + (size_t)tap*TAPF + rem*4) = q;
    }
  };

  if constexpr (SALL){
    stage(0);
    __syncthreads();
  }

  if constexpr (TOW>0){
    // ---- row-band LDS path ----
    const int pb0 = bx * (256/COQ);      // first pixel of this block
    const int r0  = pb0 / TOW;           // first output row index (global)
    const int oy0 = r0 % OH;
    const int n0  = r0 / OH;             // ROWS rows never cross n (OH%ROWS==0)
    const int myrow = (p0 - pb0) / TOW;
    const int oxl   = (p0 - pb0) - myrow*TOW;

    for (int ky=0; ky<KH; ky++){
      __syncthreads();
      if constexpr (!SALL) stage(ky*KW);
      if constexpr (CLEN==3){
        constexpr int INS = ROWS*SPAN;
        for (int v=(int)threadIdx.x; v<INS; v+=256){
          int r  = v / SPAN;
          int ixo= v - r*SPAN;
          int iy = (oy0+r)*STRIDE - PAD + ky;
          int ix = ixo - PAD;
          bool ok = iy>=0 && iy<H && ix>=0 && ix<W;
          const float* ip = in + ((size_t)(n0*H+iy)*W + ix)*CIN;
          si[v*3+0] = ok?ip[0]:0.f;
          si[v*3+1] = ok?ip[1]:0.f;
          si[v*3+2] = ok?ip[2]:0.f;
        }
      } else {
        constexpr int INQ = ROWS*CQ4*SPAN;
        for (int v=(int)threadIdx.x; v<INQ; v+=256){
          int r  = v / (CQ4*SPAN);
          int rm = v - r*(CQ4*SPAN);
          int q  = rm / SPAN;
          int ixo= rm - q*SPAN;
          int iy = (oy0+r)*STRIDE - PAD + ky;
          int ix = ixo - PAD;
          bool ok = iy>=0 && iy<H && ix>=0 && ix<W;
          float4 val = ok ? *(const float4*)(in + ((size_t)(n0*H+iy)*W + ix)*CIN + ci_off + q*4)
                          : make_float4(0.f,0.f,0.f,0.f);
          *(float4*)&si[(size_t)v*4] = val;
        }
      }
      __syncthreads();
      const float* swr = SALL ? sw + (size_t)ky*KW*TAPF : sw;
      for (int kx=0; kx<KW; kx++){
        const float* swt = swr + (size_t)kx*TAPF;
        const int ib = oxl*STRIDE + kx;
        if constexpr (CLEN==3){
          float wv[3][4];
          *(float4*)wv[0]=*(const float4*)(swt + 0*COB + co);
          *(float4*)wv[1]=*(const float4*)(swt + 1*COB + co);
          *(float4*)wv[2]=*(const float4*)(swt + 2*COB + co);
          const float* sp = &si[(size_t)(myrow*SPAN + ib)*3];
          float v0=sp[0], v1=sp[1], v2=sp[2];
#pragma unroll
          for (int j=0;j<4;j++)
            acc[0][j]=fmaf(v0,wv[0][j],fmaf(v1,wv[1][j],fmaf(v2,wv[2][j],acc[0][j])));
        } else {
#pragma unroll 2
          for (int c=0; c<CQ4; c++){
            float wv[4][4];
#pragma unroll
            for (int r=0;r<4;r++)
              *(float4*)wv[r] = *(const float4*)(swt + (c*4+r)*COB + co);
            float va[4];
            *(float4*)va = *(const float4*)&si[(size_t)((myrow*CQ4 + c)*SPAN + ib)*4];
#pragma unroll
            for (int r=0;r<4;r++)
#pragma unroll
              for (int j=0;j<4;j++)
                acc[0][j]=fmaf(va[r],wv[r][j],acc[0][j]);
          }
        }
      }
    }
  } else {
    // ---- r8-EXACT path ----
    for (int ky=0; ky<KH; ky++){
      if constexpr (!SALL){
        __syncthreads();
        stage(ky*KW);
        __syncthreads();
      }
      const float* swr = SALL ? sw + (size_t)ky*KW*TAPF : sw;
      for (int kx=0; kx<KW; kx++){
        const float* swt = swr + (size_t)kx*TAPF;
        const float* ip[NPIX]; bool ok[NPIX];
#pragma unroll
        for (int t=0;t<NPIX;t++){
          int iy=iy0[t]+ky, ix=ix0[t]+kx;
          ok[t]=pv[t] && iy>=0 && iy<H && ix>=0 && ix<W;
          ip[t]=base[t]+(size_t)(iy*W+ix)*CIN;
        }
        if constexpr (CLEN==3){
          float wv[3][4];
          *(float4*)wv[0]=*(const float4*)(swt + 0*COB + co);
          *(float4*)wv[1]=*(const float4*)(swt + 1*COB + co);
          *(float4*)wv[2]=*(const float4*)(swt + 2*COB + co);
#pragma unroll
          for (int t=0;t<NPIX;t++){
            float v0=ok[t]?ip[t][0]:0.f;
            float v1=ok[t]?ip[t][1]:0.f;
            float v2=ok[t]?ip[t][2]:0.f;
#pragma unroll
            for (int j=0;j<4;j++)
              acc[t][j]=fmaf(v0,wv[0][j],fmaf(v1,wv[1][j],fmaf(v2,wv[2][j],acc[t][j])));
          }
        } else {
#pragma unroll 2
          for (int ci=0; ci<CLEN; ci+=4){
            float wv[4][4];
#pragma unroll
            for (int r=0;r<4;r++)
              *(float4*)wv[r] = *(const float4*)(swt + (ci+r)*COB + co);
#pragma unroll
            for (int t=0;t<NPIX;t++){
              float va[4];
              *(float4*)va = ok[t] ? *(const float4*)(ip[t]+ci)
                                   : make_float4(0.f,0.f,0.f,0.f);
#pragma unroll
              for (int r=0;r<4;r++)
#pragma unroll
                for (int j=0;j<4;j++)
                  acc[t][j]=fmaf(va[r],wv[r][j],acc[t][j]);
            }
          }
        }
      }
    }
  }

  float bv[4]={0.f,0.f,0.f,0.f};
  if constexpr (BIAS) *(float4*)bv = *(const float4*)(bias+gco);
#pragma unroll
  for (int t=0;t<NPIX;t++) if (pv[t]){
    float o[4];
#pragma unroll
    for (int j=0;j<4;j++){
      float v = acc[t][j]+bv[j];
      o[j] = ACT ? silu_f(v) : v;
    }
    *(float4*)(out + (size_t)(p0+t)*COUT + gco) = *(float4*)o;
  }
}

// ---------------------------------------------------------------------------
// reduce G partials (stride n) + bias + optional silu. (FROZEN)
// ---------------------------------------------------------------------------
template<int G,int COUT,bool ACT>
__global__ __launch_bounds__(256) void reduce_k(
    const float* __restrict__ p, const float* __restrict__ bias,
    float* __restrict__ out, int n)
{
  int i = (blockIdx.x*256+threadIdx.x)*4;
  if (i>=n) return;
  float a[4]; *(float4*)a = *(const float4*)(p+i);
#pragma unroll
  for (int g=1; g<G; g++){
    float b[4]; *(float4*)b = *(const float4*)(p+(size_t)g*n+i);
#pragma unroll
    for (int j=0;j<4;j++) a[j]+=b[j];
  }
  float bv[4]; *(float4*)bv = *(const float4*)(bias + (i % COUT));
#pragma unroll
  for (int j=0;j<4;j++){
    float v=a[j]+bv[j];
    a[j] = ACT ? silu_f(v) : v;
  }
  *(float4*)(out+i) = *(float4*)a;
}

// ---------------------------------------------------------------------------
// conv_transpose 5x5 s2 SAME (verified r0 mapping), per-tap LDS weight stage.
// parity = b&3, ci-group = (b>>2)&(G-1), spatial = b>>(2+GSH). r8-EXACT.
// ---------------------------------------------------------------------------
template<int CIN,int COUT,int NPIX,int G,bool DIRECT>
__global__ __launch_bounds__(256) void tconv_k(
    const float* __restrict__ in, const float* __restrict__ w,
    const float* __restrict__ bias, float* __restrict__ out,
    int N,int H,int W,int OH,int OW)
{
  constexpr int COQ  = COUT/4;
  constexpr int CLEN = CIN/G;
  constexpr int GSH  = LOG2<G>::v;
  constexpr int TAPF = CLEN*COUT;
  __shared__ float sw[TAPF];
  const int par = blockIdx.x & 3;
  const int py = par>>1, px = par&1;
  const int g  = (blockIdx.x>>2) & (G-1);
  const int bx = blockIdx.x >> (2+GSH);
  const int NKY = py?3:2, NKX = px?3:2;
  const int OHh=OH>>1, OWh=OW>>1;
  const int total = N*OHh*OWh;
  if (G>1) out += (size_t)g * N*OH*OW*COUT;

  int idx = bx*256 + (int)threadIdx.x;
  int cq = idx % COQ;
  int pg = idx / COQ;
  int co = cq*4;
  int p0 = pg*NPIX;

  float acc[NPIX][4] = {};
  int yy[NPIX], xx[NPIX], nn[NPIX]; const float* base[NPIX]; bool pv[NPIX];
#pragma unroll
  for (int t=0;t<NPIX;t++){
    int p=p0+t; pv[t]=(p<total); int pp=pv[t]?p:0;
    xx[t]=pp%OWh; int r=pp/OWh; yy[t]=r%OHh; nn[t]=r/OHh;
    base[t]=in+(size_t)nn[t]*H*W*CIN + g*CLEN;
  }

  for (int j=0;j<NKY;j++){
    int ky = 2*j + (py?0:1);
    for (int i=0;i<NKX;i++){
      int kx = 2*i + (px?0:1);
      __syncthreads();
      {
        constexpr int V = TAPF/4;
        const float4* src = (const float4*)(w + ((size_t)(ky*5+kx)*CIN + g*CLEN)*COUT);
        for (int v=threadIdx.x; v<V; v+=256) ((float4*)sw)[v]=src[v];
      }
      __syncthreads();
      const float* ip[NPIX]; bool ok[NPIX];
#pragma unroll
      for (int t=0;t<NPIX;t++){
        int iy=yy[t]+j-1, ix=xx[t]+i-1;
        ok[t]=pv[t] && iy>=0 && iy<H && ix>=0 && ix<W;
        ip[t]=base[t]+(size_t)(iy*W+ix)*CIN;
      }
#pragma unroll 2
      for (int ci=0; ci<CLEN; ci+=4){
        float wv[4][4];
#pragma unroll
        for (int r=0;r<4;r++)
          *(float4*)wv[r] = *(const float4*)(sw + (ci+r)*COUT + co);
#pragma unroll
        for (int t=0;t<NPIX;t++){
          float va[4];
          *(float4*)va = ok[t] ? *(const float4*)(ip[t]+ci)
                               : make_float4(0.f,0.f,0.f,0.f);
#pragma unroll
          for (int r=0;r<4;r++)
#pragma unroll
            for (int jj=0;jj<4;jj++)
              acc[t][jj]=fmaf(va[r],wv[r][jj],acc[t][jj]);
        }
      }
    }
  }

  float bv[4]={0.f,0.f,0.f,0.f};
  if constexpr (DIRECT) *(float4*)bv = *(const float4*)(bias+co);
#pragma unroll
  for (int t=0;t<NPIX;t++) if (pv[t]){
    float o[4];
#pragma unroll
    for (int jj=0;jj<4;jj++){
      float v = acc[t][jj]+bv[jj];
      o[jj] = DIRECT ? silu_f(v) : v;
    }
    *(float4*)(out + (((size_t)nn[t]*OH + (2*yy[t]+py))*OW + (2*xx[t]+px))*COUT + co) = *(float4*)o;
  }
}

// ---------------------------------------------------------------------------
// VQ fused with conv3c 2-partial reduction + bias (round-2 EXACT — FROZEN).
// ---------------------------------------------------------------------------
__global__ __launch_bounds__(256) void vq_k(
    const float* __restrict__ p, const float* __restrict__ bias,
    const float* __restrict__ cb, float* __restrict__ q, int NLat)
{
  __shared__ float slat[4][128];
  int wave = threadIdx.x >> 6;
  int lane = threadIdx.x & 63;
  int l = blockIdx.x*4 + wave;
  if (l >= NLat) return;
  const float* p0 = p + (size_t)l*128;
  const float* p1 = p0 + (size_t)NLat*128;
  slat[wave][lane]    = p0[lane]    + p1[lane]    + bias[lane];
  slat[wave][lane+64] = p0[lane+64] + p1[lane+64] + bias[lane+64];

  float bestd = INFINITY; int besti = 0;
  for (int c0=0;c0<256;c0+=64){
    int c = c0 + lane;
    const float* cp = cb + (size_t)c*128;
    float d = 0.f;
#pragma unroll 8
    for (int k=0;k<128;k+=4){
      float4 cv = *reinterpret_cast<const float4*>(cp+k);
      float d0 = slat[wave][k+0]-cv.x;
      float d1 = slat[wave][k+1]-cv.y;
      float d2 = slat[wave][k+2]-cv.z;
      float d3 = slat[wave][k+3]-cv.w;
      d += d0*d0; d += d1*d1; d += d2*d2; d += d3*d3;
    }
    if (d < bestd) { bestd = d; besti = c; }
  }
  for (int off=32; off; off>>=1){
    float od = __shfl_down(bestd, off);
    int   oi = __shfl_down(besti, off);
    if (od < bestd || (od == bestd && oi < besti)) { bestd=od; besti=oi; }
  }
  besti = __shfl(besti, 0);
  const float* cp = cb + (size_t)besti*128;
  float* qp = q + (size_t)l*128;
  qp[lane]    = cp[lane];
  qp[lane+64] = cp[lane+64];
}

// ---------------------------------------------------------------------------
// Final 3x3 conv 32->3 split over ky rows (g = blockIdx%3). Writes partials.
// ---------------------------------------------------------------------------
__global__ __launch_bounds__(256) void conv_last_k(
    const float* __restrict__ in, const float* __restrict__ w,
    float* __restrict__ p, int N,int H,int W)
{
  int g = blockIdx.x % 3;
  int bx = blockIdx.x / 3;
  int pix = bx*256 + threadIdx.x;
  int total = N*H*W;
  if (pix>=total) return;
  int x = pix % W; int r = pix / W; int y = r % H; int n = r / H;
  float a0=0.f, a1=0.f, a2=0.f;
  int iy = y + g - 1;
  if (iy>=0 && iy<H){
    const float* base = in + ((size_t)n*H + iy)*W*32;
    for (int kx=0;kx<3;kx++){
      int ix=x+kx-1; if(ix<0||ix>=W) continue;
      const float* ip = base + (size_t)ix*32;
      const float* wp = w + (size_t)((g*3+kx)*32)*3;
#pragma unroll
      for (int ci=0;ci<32;ci+=4){
        float va[4]; *(float4*)va = *(const float4*)(ip+ci);
        float wv[12];
        *(float4*)(wv+0) = *(const float4*)(wp+ci*3+0);
        *(float4*)(wv+4) = *(const float4*)(wp+ci*3+4);
        *(float4*)(wv+8) = *(const float4*)(wp+ci*3+8);
#pragma unroll
        for (int r2=0;r2<4;r2++){
          a0 = fmaf(va[r2], wv[r2*3+0], a0);
          a1 = fmaf(va[r2], wv[r2*3+1], a1);
          a2 = fmaf(va[r2], wv[r2*3+2], a2);
        }
      }
    }
  }
  float* pp = p + (size_t)g*total*3 + (size_t)pix*3;
  pp[0]=a0; pp[1]=a1; pp[2]=a2;
}

__global__ __launch_bounds__(256) void reduce_last_k(
    const float* __restrict__ p, const float* __restrict__ bias,
    float* __restrict__ out, int n)
{
  int i = (blockIdx.x*256+threadIdx.x)*4;
  if (i>=n) return;
  float a[4]; *(float4*)a = *(const float4*)(p+i);
#pragma unroll
  for (int g=1; g<3; g++){
    float b[4]; *(float4*)b = *(const float4*)(p+(size_t)g*n+i);
#pragma unroll
    for (int j=0;j<4;j++) a[j]+=b[j];
  }
  float o[4];
#pragma unroll
  for (int j=0;j<4;j++) o[j] = a[j] + bias[(i+j)%3];
  *(float4*)(out+i) = *(float4*)o;
}

extern "C" void kernel_launch(void* const* d_in, const int* in_sizes, int n_in,
                              void* d_out, int out_size, void* d_ws, size_t ws_size,
                              hipStream_t stream) {
  const float* x    = (const float*)d_in[0];
  const float* k1   = (const float*)d_in[1];  const float* b1  = (const float*)d_in[2];
  const float* k1c  = (const float*)d_in[3];  const float* b1c = (const float*)d_in[4];
  const float* k2   = (const float*)d_in[5];  const float* b2  = (const float*)d_in[6];
  const float* k2c  = (const float*)d_in[7];  const float* b2c = (const float*)d_in[8];
  const float* k3   = (const float*)d_in[9];  const float* b3  = (const float*)d_in[10];
  const float* k3c  = (const float*)d_in[11]; const float* b3c = (const float*)d_in[12];
  const float* cb   = (const float*)d_in[13];
  const float* tk1  = (const float*)d_in[14]; const float* tb1  = (const float*)d_in[15];
  const float* tk1c = (const float*)d_in[16]; const float* tb1c = (const float*)d_in[17];
  const float* tk2  = (const float*)d_in[18]; const float* tb2  = (const float*)d_in[19];
  const float* tk2c = (const float*)d_in[20]; const float* tb2c = (const float*)d_in[21];
  const float* tk3  = (const float*)d_in[22]; const float* tb3  = (const float*)d_in[23];
  const float* tk3c = (const float*)d_in[24]; const float* tb3c = (const float*)d_in[25];
  float* out = (float*)d_out;

  float* S  = (float*)d_ws;
  float* W0 = S;                 // [0 .. 1M) floats
  float* W1 = S + 1048576;       // [1M .. 2M)
  float* P  = S + 2097152;       // [2M .. 6M)
  dim3 blk(256);

  // ---- encoder: G-splits + fmaf order FROZEN; TOW row-band everywhere ----
  // conv1: 1 row (OW=64), sw SALL 23.2KB, si 1.6KB
  conv_k<11,11,2,4,  3, 32,1,true ,true ,1,2,64><<<1024,blk,0,stream>>>(x,  k1,  b1,  W0, 8,128,128,64,64);
  // conv1c: 1 row (OW=64), sw SALL 18KB, si 8.25KB
  conv_k< 3, 3,1,1, 32, 32,1,true ,true ,1,2,64><<<1024,blk,0,stream>>>(W0, k1c, b1c, W1, 8,64,64,64,64);
  // conv2: 1 row (OW=32), per-ky sw 22.5KB, si 4.7KB (r14-proven)
  conv_k<11,11,2,4, 32, 64,1,false,false,2,2,32><<<1024,blk,0,stream>>>(W1, k2,  nullptr, P, 8,64,64,32,32);
  reduce_k<2, 64,true><<< 512,blk,0,stream>>>(P, b2,  W0, 524288);
  // conv2c: 1 row (OW=32), per-ky sw 24KB, si 8.5KB
  conv_k< 3, 3,1,1, 64, 64,1,true ,true ,1,2,32><<< 512,blk,0,stream>>>(W0, k2c, b2c, W1, 8,32,32,32,32);
  // conv3: 2 rows (OW=16), per-ky sw 22.5KB, si 9.2KB (r14-proven)
  conv_k<11,11,2,4, 64,128,1,false,false,4,4,16><<<1024,blk,0,stream>>>(W1, k3,  nullptr, P, 8,32,32,16,16);
  reduce_k<4,128,true><<< 256,blk,0,stream>>>(P, b3,  W0, 262144);
  // conv3c: 2 rows (OW=16), per-ky sw 24KB, si 9.2KB
  conv_k< 3, 3,1,1,128,128,1,false,false,2,4,16><<< 512,blk,0,stream>>>(W0, k3c, nullptr, P, 8,16,16,16,16);
  // ---- VQ: r2-exact 2-partial reduce + argmin + gather (FROZEN) ----
  vq_k<<<512,blk,0,stream>>>(P, b3c, cb, W1, 2048);
  // ---- decoder (tconvs r8-exact; 3x3s row-banded, CS numerics-free) ----
  tconv_k<128,64,1,4,false><<<2048,blk,0,stream>>>(W1, tk1, nullptr, P, 8,16,16,32,32);
  reduce_k<4, 64,true><<< 512,blk,0,stream>>>(P, tb1,  W0, 524288);
  // tk1c: CS4 -> sw SALL 18KB; 2 rows (OW=32), si 8.7KB; grid 1024 unchanged
  conv_k< 3, 3,1,1, 64, 64,1,false,false,2,4,32><<<1024,blk,0,stream>>>(W0, tk1c, nullptr, P, 8,32,32,32,32);
  reduce_k<2, 64,true><<< 512,blk,0,stream>>>(P, tb1c, W1, 524288);
  tconv_k< 64,32,1,2,false><<<2048,blk,0,stream>>>(W1, tk2, nullptr, P, 8,32,32,64,64);
  reduce_k<2, 32,true><<<1024,blk,0,stream>>>(P, tb2,  W0, 1048576);
  // tk2c: 1 row (OW=64), sw SALL 18KB, si 8.25KB
  conv_k< 3, 3,1,1, 32, 32,1,true ,true ,1,2,64><<<1024,blk,0,stream>>>(W0, tk2c, tb2c, W1, 8,64,64,64,64);
  tconv_k< 32,32,2,1,true ><<<2048,blk,0,stream>>>(W1, tk3, tb3, P, 8,64,64,128,128);
  conv_last_k<<<1536,blk,0,stream>>>(P, tk3c, S, 8,128,128);
  reduce_last_k<<<384,blk,0,stream>>>(S, tb3c, out, 393216);
}

// Round 16
// 465.327 us; speedup vs baseline: 9.2703x; 1.0674x over previous
//
#include <hip/hip_runtime.h>

#define DI __device__ __forceinline__
DI float silu_f(float x){ return x * (1.0f/(1.0f+__expf(-x))); }

template<int X> struct LOG2 { static constexpr int v = 1 + LOG2<X/2>::v; };
template<> struct LOG2<1> { static constexpr int v = 0; };

// ---------------------------------------------------------------------------
// Direct conv, NHWC in, HWIO weights, LDS-staged weight slices.
// Thread = NPIX pixels x 4 co. G: ci-split (FROZEN — VQ argmin is sensitive
// to latent rounding). CS: co-split across blocks (numerics-free).
// TOW>0 (r14/r15-proven bit-identical): block = whole output row(s); per ky,
// stage the input row band into LDS once -> tap loop is pure LDS.
// r16: TOW path supports NPIX=2 (conv2/conv3): each weight quad read feeds
// 2 pixels (-40% LDS ops/FMA) and each per-ky stage barrier amortizes over
// 2x compute. Pixel pairs never straddle rows (TOW even, pairs aligned).
// r9/r13 lesson: NO register-level prefetch (compiler hoists -> spills).
// Per-output fmaf chain order (ky->kx->ci asc->r asc) UNCHANGED everywhere.
// ---------------------------------------------------------------------------
template<int KH,int KW,int STRIDE,int PAD,int CIN,int COUT,int NPIX,
         bool ACT,bool BIAS,int G,int CS,int TOW>
__global__ __launch_bounds__(256) void conv_k(
    const float* __restrict__ in, const float* __restrict__ w,
    const float* __restrict__ bias, float* __restrict__ out,
    int N,int H,int W,int OH,int OW)
{
  constexpr int CLEN = CIN/G;
  constexpr int COB  = COUT/CS;
  constexpr int COQ  = COB/4;
  constexpr int GSH  = LOG2<G>::v;
  constexpr int CSH  = LOG2<CS>::v;
  constexpr int TAPF = CLEN*COB;
  constexpr bool SALL = (KH*KW*TAPF*4) <= 47*1024;
  constexpr int NTAP = SALL ? KH*KW : KW;
  static_assert(CLEN==3 || (CLEN%4)==0, "ci");
  __shared__ float sw[NTAP*TAPF];
  // input row-band staging (TOW>0 only)
  constexpr int SPAN = (TOW>0) ? (TOW-1)*STRIDE + KW : 1;
  constexpr int ROWS = (TOW>0) ? ((256/COQ)*NPIX)/TOW : 1;
  constexpr int CQ4  = (TOW>0 && CLEN!=3) ? CLEN/4 : 1;
  constexpr int SI_F = (TOW==0) ? 1 : (CLEN==3 ? ROWS*SPAN*3 : ROWS*CQ4*SPAN*4);
  __shared__ float si[SI_F];
  static_assert(TOW==0 || NPIX<=2, "tow npix");
  static_assert(TOW==0 || ((256/COQ)*NPIX) % TOW == 0, "rows");

  const int g  = blockIdx.x & (G-1);
  const int cs = (blockIdx.x >> GSH) & (CS-1);
  const int bx = blockIdx.x >> (GSH+CSH);
  const int total = N*OH*OW;
  if (G>1) out += (size_t)g * total * COUT;
  const int ci_off  = g*CLEN;
  const int co_base = cs*COB;

  int idx = bx*256 + (int)threadIdx.x;
  int cq = idx % COQ;
  int pg = idx / COQ;
  int co = cq*4;                 // within block's co slice
  int gco = co_base + co;        // global co
  int p0 = pg*NPIX;

  float acc[NPIX][4] = {};
  int iy0[NPIX], ix0[NPIX]; const float* base[NPIX]; bool pv[NPIX];
#pragma unroll
  for (int t=0;t<NPIX;t++){
    int p=p0+t; pv[t]=(p<total); int pp=pv[t]?p:0;
    int ox=pp%OW; int r=pp/OW; int oy=r%OH; int n=r/OH;
    iy0[t]=oy*STRIDE-PAD; ix0[t]=ox*STRIDE-PAD;
    base[t]=in+(size_t)n*H*W*CIN + ci_off;
  }

  auto stage = [&](int tap0){
    constexpr int TQ = TAPF/4;
    constexpr int V  = NTAP*TQ;
    for (int v=threadIdx.x; v<V; v+=256){
      int tap = v / TQ; int rem = v - tap*TQ;
      float4 q;
      if constexpr (CS==1){
        const float4* src = (const float4*)(w + ((size_t)(tap0+tap)*CIN + ci_off)*COUT);
        q = src[rem];
      } else if constexpr (CLEN==3){
        int ci = rem / (COB/4); int r2 = rem - ci*(COB/4);
        q = *(const float4*)(w + ((size_t)(tap0+tap)*CIN + ci)*COUT
                               + co_base + r2*4);
      } else {
        int ci = rem / (COB/4); int r2 = rem - ci*(COB/4);
        q = *(const float4*)(w + ((size_t)(tap0+tap)*CIN + ci_off + ci)*COUT
                               + co_base + r2*4);
      }
      *(float4*)(sw + (size_t)tap*TAPF + rem*4) = q;
    }
  };

  if constexpr (SALL){
    stage(0);
    __syncthreads();
  }

  if constexpr (TOW>0){
    // ---- row-band LDS path ----
    const int pb0 = bx * ((256/COQ)*NPIX);   // first pixel of this block
    const int r0  = pb0 / TOW;               // first output row index (global)
    const int oy0 = r0 % OH;
    const int n0  = r0 / OH;                 // ROWS rows never cross n
    int myrow[NPIX], oxl[NPIX];
#pragma unroll
    for (int t=0;t<NPIX;t++){
      int pl = p0 + t - pb0;
      myrow[t] = pl / TOW;
      oxl[t]   = pl - myrow[t]*TOW;
    }

    for (int ky=0; ky<KH; ky++){
      __syncthreads();
      if constexpr (!SALL) stage(ky*KW);
      if constexpr (CLEN==3){
        constexpr int INS = ROWS*SPAN;
        for (int v=(int)threadIdx.x; v<INS; v+=256){
          int r  = v / SPAN;
          int ixo= v - r*SPAN;
          int iy = (oy0+r)*STRIDE - PAD + ky;
          int ix = ixo - PAD;
          bool ok = iy>=0 && iy<H && ix>=0 && ix<W;
          const float* ip = in + ((size_t)(n0*H+iy)*W + ix)*CIN;
          si[v*3+0] = ok?ip[0]:0.f;
          si[v*3+1] = ok?ip[1]:0.f;
          si[v*3+2] = ok?ip[2]:0.f;
        }
      } else {
        constexpr int INQ = ROWS*CQ4*SPAN;
        for (int v=(int)threadIdx.x; v<INQ; v+=256){
          int r  = v / (CQ4*SPAN);
          int rm = v - r*(CQ4*SPAN);
          int q  = rm / SPAN;
          int ixo= rm - q*SPAN;
          int iy = (oy0+r)*STRIDE - PAD + ky;
          int ix = ixo - PAD;
          bool ok = iy>=0 && iy<H && ix>=0 && ix<W;
          float4 val = ok ? *(const float4*)(in + ((size_t)(n0*H+iy)*W + ix)*CIN + ci_off + q*4)
                          : make_float4(0.f,0.f,0.f,0.f);
          *(float4*)&si[(size_t)v*4] = val;
        }
      }
      __syncthreads();
      const float* swr = SALL ? sw + (size_t)ky*KW*TAPF : sw;
      for (int kx=0; kx<KW; kx++){
        const float* swt = swr + (size_t)kx*TAPF;
        if constexpr (CLEN==3){
          float wv[3][4];
          *(float4*)wv[0]=*(const float4*)(swt + 0*COB + co);
          *(float4*)wv[1]=*(const float4*)(swt + 1*COB + co);
          *(float4*)wv[2]=*(const float4*)(swt + 2*COB + co);
#pragma unroll
          for (int t=0;t<NPIX;t++){
            const float* sp = &si[(size_t)(myrow[t]*SPAN + oxl[t]*STRIDE + kx)*3];
            float v0=sp[0], v1=sp[1], v2=sp[2];
#pragma unroll
            for (int j=0;j<4;j++)
              acc[t][j]=fmaf(v0,wv[0][j],fmaf(v1,wv[1][j],fmaf(v2,wv[2][j],acc[t][j])));
          }
        } else {
#pragma unroll 2
          for (int c=0; c<CQ4; c++){
            float wv[4][4];
#pragma unroll
            for (int r=0;r<4;r++)
              *(float4*)wv[r] = *(const float4*)(swt + (c*4+r)*COB + co);
#pragma unroll
            for (int t=0;t<NPIX;t++){
              float va[4];
              *(float4*)va = *(const float4*)&si[(size_t)((myrow[t]*CQ4 + c)*SPAN + oxl[t]*STRIDE + kx)*4];
#pragma unroll
              for (int r=0;r<4;r++)
#pragma unroll
                for (int j=0;j<4;j++)
                  acc[t][j]=fmaf(va[r],wv[r][j],acc[t][j]);
            }
          }
        }
      }
    }
  } else {
    // ---- r8-EXACT path ----
    for (int ky=0; ky<KH; ky++){
      if constexpr (!SALL){
        __syncthreads();
        stage(ky*KW);
        __syncthreads();
      }
      const float* swr = SALL ? sw + (size_t)ky*KW*TAPF : sw;
      for (int kx=0; kx<KW; kx++){
        const float* swt = swr + (size_t)kx*TAPF;
        const float* ip[NPIX]; bool ok[NPIX];
#pragma unroll
        for (int t=0;t<NPIX;t++){
          int iy=iy0[t]+ky, ix=ix0[t]+kx;
          ok[t]=pv[t] && iy>=0 && iy<H && ix>=0 && ix<W;
          ip[t]=base[t]+(size_t)(iy*W+ix)*CIN;
        }
        if constexpr (CLEN==3){
          float wv[3][4];
          *(float4*)wv[0]=*(const float4*)(swt + 0*COB + co);
          *(float4*)wv[1]=*(const float4*)(swt + 1*COB + co);
          *(float4*)wv[2]=*(const float4*)(swt + 2*COB + co);
#pragma unroll
          for (int t=0;t<NPIX;t++){
            float v0=ok[t]?ip[t][0]:0.f;
            float v1=ok[t]?ip[t][1]:0.f;
            float v2=ok[t]?ip[t][2]:0.f;
#pragma unroll
            for (int j=0;j<4;j++)
              acc[t][j]=fmaf(v0,wv[0][j],fmaf(v1,wv[1][j],fmaf(v2,wv[2][j],acc[t][j])));
          }
        } else {
#pragma unroll 2
          for (int ci=0; ci<CLEN; ci+=4){
            float wv[4][4];
#pragma unroll
            for (int r=0;r<4;r++)
              *(float4*)wv[r] = *(const float4*)(swt + (ci+r)*COB + co);
#pragma unroll
            for (int t=0;t<NPIX;t++){
              float va[4];
              *(float4*)va = ok[t] ? *(const float4*)(ip[t]+ci)
                                   : make_float4(0.f,0.f,0.f,0.f);
#pragma unroll
              for (int r=0;r<4;r++)
#pragma unroll
                for (int j=0;j<4;j++)
                  acc[t][j]=fmaf(va[r],wv[r][j],acc[t][j]);
            }
          }
        }
      }
    }
  }

  float bv[4]={0.f,0.f,0.f,0.f};
  if constexpr (BIAS) *(float4*)bv = *(const float4*)(bias+gco);
#pragma unroll
  for (int t=0;t<NPIX;t++) if (pv[t]){
    float o[4];
#pragma unroll
    for (int j=0;j<4;j++){
      float v = acc[t][j]+bv[j];
      o[j] = ACT ? silu_f(v) : v;
    }
    *(float4*)(out + (size_t)(p0+t)*COUT + gco) = *(float4*)o;
  }
}

// ---------------------------------------------------------------------------
// reduce G partials (stride n) + bias + optional silu. (FROZEN)
// ---------------------------------------------------------------------------
template<int G,int COUT,bool ACT>
__global__ __launch_bounds__(256) void reduce_k(
    const float* __restrict__ p, const float* __restrict__ bias,
    float* __restrict__ out, int n)
{
  int i = (blockIdx.x*256+threadIdx.x)*4;
  if (i>=n) return;
  float a[4]; *(float4*)a = *(const float4*)(p+i);
#pragma unroll
  for (int g=1; g<G; g++){
    float b[4]; *(float4*)b = *(const float4*)(p+(size_t)g*n+i);
#pragma unroll
    for (int j=0;j<4;j++) a[j]+=b[j];
  }
  float bv[4]; *(float4*)bv = *(const float4*)(bias + (i % COUT));
#pragma unroll
  for (int j=0;j<4;j++){
    float v=a[j]+bv[j];
    a[j] = ACT ? silu_f(v) : v;
  }
  *(float4*)(out+i) = *(float4*)a;
}

// ---------------------------------------------------------------------------
// conv_transpose 5x5 s2 SAME (verified r0 mapping), per-tap LDS weight stage.
// parity = b&3, ci-group = (b>>2)&(G-1), spatial = b>>(2+GSH). r8-EXACT.
// ---------------------------------------------------------------------------
template<int CIN,int COUT,int NPIX,int G,bool DIRECT>
__global__ __launch_bounds__(256) void tconv_k(
    const float* __restrict__ in, const float* __restrict__ w,
    const float* __restrict__ bias, float* __restrict__ out,
    int N,int H,int W,int OH,int OW)
{
  constexpr int COQ  = COUT/4;
  constexpr int CLEN = CIN/G;
  constexpr int GSH  = LOG2<G>::v;
  constexpr int TAPF = CLEN*COUT;
  __shared__ float sw[TAPF];
  const int par = blockIdx.x & 3;
  const int py = par>>1, px = par&1;
  const int g  = (blockIdx.x>>2) & (G-1);
  const int bx = blockIdx.x >> (2+GSH);
  const int NKY = py?3:2, NKX = px?3:2;
  const int OHh=OH>>1, OWh=OW>>1;
  const int total = N*OHh*OWh;
  if (G>1) out += (size_t)g * N*OH*OW*COUT;

  int idx = bx*256 + (int)threadIdx.x;
  int cq = idx % COQ;
  int pg = idx / COQ;
  int co = cq*4;
  int p0 = pg*NPIX;

  float acc[NPIX][4] = {};
  int yy[NPIX], xx[NPIX], nn[NPIX]; const float* base[NPIX]; bool pv[NPIX];
#pragma unroll
  for (int t=0;t<NPIX;t++){
    int p=p0+t; pv[t]=(p<total); int pp=pv[t]?p:0;
    xx[t]=pp%OWh; int r=pp/OWh; yy[t]=r%OHh; nn[t]=r/OHh;
    base[t]=in+(size_t)nn[t]*H*W*CIN + g*CLEN;
  }

  for (int j=0;j<NKY;j++){
    int ky = 2*j + (py?0:1);
    for (int i=0;i<NKX;i++){
      int kx = 2*i + (px?0:1);
      __syncthreads();
      {
        constexpr int V = TAPF/4;
        const float4* src = (const float4*)(w + ((size_t)(ky*5+kx)*CIN + g*CLEN)*COUT);
        for (int v=threadIdx.x; v<V; v+=256) ((float4*)sw)[v]=src[v];
      }
      __syncthreads();
      const float* ip[NPIX]; bool ok[NPIX];
#pragma unroll
      for (int t=0;t<NPIX;t++){
        int iy=yy[t]+j-1, ix=xx[t]+i-1;
        ok[t]=pv[t] && iy>=0 && iy<H && ix>=0 && ix<W;
        ip[t]=base[t]+(size_t)(iy*W+ix)*CIN;
      }
#pragma unroll 2
      for (int ci=0; ci<CLEN; ci+=4){
        float wv[4][4];
#pragma unroll
        for (int r=0;r<4;r++)
          *(float4*)wv[r] = *(const float4*)(sw + (ci+r)*COUT + co);
#pragma unroll
        for (int t=0;t<NPIX;t++){
          float va[4];
          *(float4*)va = ok[t] ? *(const float4*)(ip[t]+ci)
                               : make_float4(0.f,0.f,0.f,0.f);
#pragma unroll
          for (int r=0;r<4;r++)
#pragma unroll
            for (int jj=0;jj<4;jj++)
              acc[t][jj]=fmaf(va[r],wv[r][jj],acc[t][jj]);
        }
      }
    }
  }

  float bv[4]={0.f,0.f,0.f,0.f};
  if constexpr (DIRECT) *(float4*)bv = *(const float4*)(bias+co);
#pragma unroll
  for (int t=0;t<NPIX;t++) if (pv[t]){
    float o[4];
#pragma unroll
    for (int jj=0;jj<4;jj++){
      float v = acc[t][jj]+bv[jj];
      o[jj] = DIRECT ? silu_f(v) : v;
    }
    *(float4*)(out + (((size_t)nn[t]*OH + (2*yy[t]+py))*OW + (2*xx[t]+px))*COUT + co) = *(float4*)o;
  }
}

// ---------------------------------------------------------------------------
// VQ fused with conv3c 2-partial reduction + bias (round-2 EXACT — FROZEN).
// ---------------------------------------------------------------------------
__global__ __launch_bounds__(256) void vq_k(
    const float* __restrict__ p, const float* __restrict__ bias,
    const float* __restrict__ cb, float* __restrict__ q, int NLat)
{
  __shared__ float slat[4][128];
  int wave = threadIdx.x >> 6;
  int lane = threadIdx.x & 63;
  int l = blockIdx.x*4 + wave;
  if (l >= NLat) return;
  const float* p0 = p + (size_t)l*128;
  const float* p1 = p0 + (size_t)NLat*128;
  slat[wave][lane]    = p0[lane]    + p1[lane]    + bias[lane];
  slat[wave][lane+64] = p0[lane+64] + p1[lane+64] + bias[lane+64];

  float bestd = INFINITY; int besti = 0;
  for (int c0=0;c0<256;c0+=64){
    int c = c0 + lane;
    const float* cp = cb + (size_t)c*128;
    float d = 0.f;
#pragma unroll 8
    for (int k=0;k<128;k+=4){
      float4 cv = *reinterpret_cast<const float4*>(cp+k);
      float d0 = slat[wave][k+0]-cv.x;
      float d1 = slat[wave][k+1]-cv.y;
      float d2 = slat[wave][k+2]-cv.z;
      float d3 = slat[wave][k+3]-cv.w;
      d += d0*d0; d += d1*d1; d += d2*d2; d += d3*d3;
    }
    if (d < bestd) { bestd = d; besti = c; }
  }
  for (int off=32; off; off>>=1){
    float od = __shfl_down(bestd, off);
    int   oi = __shfl_down(besti, off);
    if (od < bestd || (od == bestd && oi < besti)) { bestd=od; besti=oi; }
  }
  besti = __shfl(besti, 0);
  const float* cp = cb + (size_t)besti*128;
  float* qp = q + (size_t)l*128;
  qp[lane]    = cp[lane];
  qp[lane+64] = cp[lane+64];
}

// ---------------------------------------------------------------------------
// Final 3x3 conv 32->3 split over ky rows (g = blockIdx%3). Writes partials.
// ---------------------------------------------------------------------------
__global__ __launch_bounds__(256) void conv_last_k(
    const float* __restrict__ in, const float* __restrict__ w,
    float* __restrict__ p, int N,int H,int W)
{
  int g = blockIdx.x % 3;
  int bx = blockIdx.x / 3;
  int pix = bx*256 + threadIdx.x;
  int total = N*H*W;
  if (pix>=total) return;
  int x = pix % W; int r = pix / W; int y = r % H; int n = r / H;
  float a0=0.f, a1=0.f, a2=0.f;
  int iy = y + g - 1;
  if (iy>=0 && iy<H){
    const float* base = in + ((size_t)n*H + iy)*W*32;
    for (int kx=0;kx<3;kx++){
      int ix=x+kx-1; if(ix<0||ix>=W) continue;
      const float* ip = base + (size_t)ix*32;
      const float* wp = w + (size_t)((g*3+kx)*32)*3;
#pragma unroll
      for (int ci=0;ci<32;ci+=4){
        float va[4]; *(float4*)va = *(const float4*)(ip+ci);
        float wv[12];
        *(float4*)(wv+0) = *(const float4*)(wp+ci*3+0);
        *(float4*)(wv+4) = *(const float4*)(wp+ci*3+4);
        *(float4*)(wv+8) = *(const float4*)(wp+ci*3+8);
#pragma unroll
        for (int r2=0;r2<4;r2++){
          a0 = fmaf(va[r2], wv[r2*3+0], a0);
          a1 = fmaf(va[r2], wv[r2*3+1], a1);
          a2 = fmaf(va[r2], wv[r2*3+2], a2);
        }
      }
    }
  }
  float* pp = p + (size_t)g*total*3 + (size_t)pix*3;
  pp[0]=a0; pp[1]=a1; pp[2]=a2;
}

__global__ __launch_bounds__(256) void reduce_last_k(
    const float* __restrict__ p, const float* __restrict__ bias,
    float* __restrict__ out, int n)
{
  int i = (blockIdx.x*256+threadIdx.x)*4;
  if (i>=n) return;
  float a[4]; *(float4*)a = *(const float4*)(p+i);
#pragma unroll
  for (int g=1; g<3; g++){
    float b[4]; *(float4*)b = *(const float4*)(p+(size_t)g*n+i);
#pragma unroll
    for (int j=0;j<4;j++) a[j]+=b[j];
  }
  float o[4];
#pragma unroll
  for (int j=0;j<4;j++) o[j] = a[j] + bias[(i+j)%3];
  *(float4*)(out+i) = *(float4*)o;
}

extern "C" void kernel_launch(void* const* d_in, const int* in_sizes, int n_in,
                              void* d_out, int out_size, void* d_ws, size_t ws_size,
                              hipStream_t stream) {
  const float* x    = (const float*)d_in[0];
  const float* k1   = (const float*)d_in[1];  const float* b1  = (const float*)d_in[2];
  const float* k1c  = (const float*)d_in[3];  const float* b1c = (const float*)d_in[4];
  const float* k2   = (const float*)d_in[5];  const float* b2  = (const float*)d_in[6];
  const float* k2c  = (const float*)d_in[7];  const float* b2c = (const float*)d_in[8];
  const float* k3   = (const float*)d_in[9];  const float* b3  = (const float*)d_in[10];
  const float* k3c  = (const float*)d_in[11]; const float* b3c = (const float*)d_in[12];
  const float* cb   = (const float*)d_in[13];
  const float* tk1  = (const float*)d_in[14]; const float* tb1  = (const float*)d_in[15];
  const float* tk1c = (const float*)d_in[16]; const float* tb1c = (const float*)d_in[17];
  const float* tk2  = (const float*)d_in[18]; const float* tb2  = (const float*)d_in[19];
  const float* tk2c = (const float*)d_in[20]; const float* tb2c = (const float*)d_in[21];
  const float* tk3  = (const float*)d_in[22]; const float* tb3  = (const float*)d_in[23];
  const float* tk3c = (const float*)d_in[24]; const float* tb3c = (const float*)d_in[25];
  float* out = (float*)d_out;

  float* S  = (float*)d_ws;
  float* W0 = S;                 // [0 .. 1M) floats
  float* W1 = S + 1048576;       // [1M .. 2M)
  float* P  = S + 2097152;       // [2M .. 6M)
  dim3 blk(256);

  // ---- encoder: G-splits + fmaf order FROZEN; TOW row-band everywhere ----
  // conv1: 1 row (OW=64), sw SALL 23.2KB, si 1.6KB
  conv_k<11,11,2,4,  3, 32,1,true ,true ,1,2,64><<<1024,blk,0,stream>>>(x,  k1,  b1,  W0, 8,128,128,64,64);
  // conv1c: 1 row (OW=64), sw SALL 18KB, si 8.25KB
  conv_k< 3, 3,1,1, 32, 32,1,true ,true ,1,2,64><<<1024,blk,0,stream>>>(W0, k1c, b1c, W1, 8,64,64,64,64);
  // conv2: NPIX=2 -> 2 rows/block, weight quads reused across 2 pixels;
  //        per-ky sw 22.5KB + si 9.3KB = 31.8KB; 512 blocks
  conv_k<11,11,2,4, 32, 64,2,false,false,2,2,32><<< 512,blk,0,stream>>>(W1, k2,  nullptr, P, 8,64,64,32,32);
  reduce_k<2, 64,true><<< 512,blk,0,stream>>>(P, b2,  W0, 524288);
  // conv2c: 1 row (OW=32), per-ky sw 24KB, si 8.5KB
  conv_k< 3, 3,1,1, 64, 64,1,true ,true ,1,2,32><<< 512,blk,0,stream>>>(W0, k2c, b2c, W1, 8,32,32,32,32);
  // conv3: NPIX=2 -> 4 rows/block; per-ky sw 22.5KB + si 10.5KB = 33KB; 512 blocks
  conv_k<11,11,2,4, 64,128,2,false,false,4,4,16><<< 512,blk,0,stream>>>(W1, k3,  nullptr, P, 8,32,32,16,16);
  reduce_k<4,128,true><<< 256,blk,0,stream>>>(P, b3,  W0, 262144);
  // conv3c: 2 rows (OW=16), per-ky sw 24KB, si 9.2KB
  conv_k< 3, 3,1,1,128,128,1,false,false,2,4,16><<< 512,blk,0,stream>>>(W0, k3c, nullptr, P, 8,16,16,16,16);
  // ---- VQ: r2-exact 2-partial reduce + argmin + gather (FROZEN) ----
  vq_k<<<512,blk,0,stream>>>(P, b3c, cb, W1, 2048);
  // ---- decoder (tconvs r8-exact; 3x3s row-banded) ----
  tconv_k<128,64,1,4,false><<<2048,blk,0,stream>>>(W1, tk1, nullptr, P, 8,16,16,32,32);
  reduce_k<4, 64,true><<< 512,blk,0,stream>>>(P, tb1,  W0, 524288);
  conv_k< 3, 3,1,1, 64, 64,1,false,false,2,4,32><<<1024,blk,0,stream>>>(W0, tk1c, nullptr, P, 8,32,32,32,32);
  reduce_k<2, 64,true><<< 512,blk,0,stream>>>(P, tb1c, W1, 524288);
  tconv_k< 64,32,1,2,false><<<2048,blk,0,stream>>>(W1, tk2, nullptr, P, 8,32,32,64,64);
  reduce_k<2, 32,true><<<1024,blk,0,stream>>>(P, tb2,  W0, 1048576);
  conv_k< 3, 3,1,1, 32, 32,1,true ,true ,1,2,64><<<1024,blk,0,stream>>>(W0, tk2c, tb2c, W1, 8,64,64,64,64);
  tconv_k< 32,32,2,1,true ><<<2048,blk,0,stream>>>(W1, tk3, tb3, P, 8,64,64,128,128);
  conv_last_k<<<1536,blk,0,stream>>>(P, tk3c, S, 8,128,128);
  reduce_last_k<<<384,blk,0,stream>>>(S, tb3c, out, 393216);
}

// Round 17
// 462.679 us; speedup vs baseline: 9.3234x; 1.0057x over previous
//
#include <hip/hip_runtime.h>

#define DI __device__ __forceinline__
DI float silu_f(float x){ return x * (1.0f/(1.0f+__expf(-x))); }

template<int X> struct LOG2 { static constexpr int v = 1 + LOG2<X/2>::v; };
template<> struct LOG2<1> { static constexpr int v = 0; };

// ---------------------------------------------------------------------------
// Direct conv, NHWC in, HWIO weights, LDS-staged weight slices.
// Thread = NPIX pixels x 4 co. G: ci-split (FROZEN — VQ argmin is sensitive
// to latent rounding). CS: co-split across blocks (numerics-free).
// TOW>0 (r14/r15/r16-proven bit-identical): block = whole output row(s);
// per ky, stage the input row band into LDS once -> tap loop is pure LDS.
// NPIX=2 on TOW path (r16-proven on conv2/conv3): weight quads reused
// across 2 pixels, per-ky stage barrier amortized over 2x compute.
// r17: NPIX=2 extended to conv1/conv1c/tk1c/tk2c (same mechanism).
// r9/r13 lesson: NO register-level prefetch (compiler hoists -> spills).
// Per-output fmaf chain order (ky->kx->ci asc->r asc) UNCHANGED everywhere.
// ---------------------------------------------------------------------------
template<int KH,int KW,int STRIDE,int PAD,int CIN,int COUT,int NPIX,
         bool ACT,bool BIAS,int G,int CS,int TOW>
__global__ __launch_bounds__(256) void conv_k(
    const float* __restrict__ in, const float* __restrict__ w,
    const float* __restrict__ bias, float* __restrict__ out,
    int N,int H,int W,int OH,int OW)
{
  constexpr int CLEN = CIN/G;
  constexpr int COB  = COUT/CS;
  constexpr int COQ  = COB/4;
  constexpr int GSH  = LOG2<G>::v;
  constexpr int CSH  = LOG2<CS>::v;
  constexpr int TAPF = CLEN*COB;
  constexpr bool SALL = (KH*KW*TAPF*4) <= 47*1024;
  constexpr int NTAP = SALL ? KH*KW : KW;
  static_assert(CLEN==3 || (CLEN%4)==0, "ci");
  __shared__ float sw[NTAP*TAPF];
  // input row-band staging (TOW>0 only)
  constexpr int SPAN = (TOW>0) ? (TOW-1)*STRIDE + KW : 1;
  constexpr int ROWS = (TOW>0) ? ((256/COQ)*NPIX)/TOW : 1;
  constexpr int CQ4  = (TOW>0 && CLEN!=3) ? CLEN/4 : 1;
  constexpr int SI_F = (TOW==0) ? 1 : (CLEN==3 ? ROWS*SPAN*3 : ROWS*CQ4*SPAN*4);
  __shared__ float si[SI_F];
  static_assert(TOW==0 || NPIX<=2, "tow npix");
  static_assert(TOW==0 || ((256/COQ)*NPIX) % TOW == 0, "rows");

  const int g  = blockIdx.x & (G-1);
  const int cs = (blockIdx.x >> GSH) & (CS-1);
  const int bx = blockIdx.x >> (GSH+CSH);
  const int total = N*OH*OW;
  if (G>1) out += (size_t)g * total * COUT;
  const int ci_off  = g*CLEN;
  const int co_base = cs*COB;

  int idx = bx*256 + (int)threadIdx.x;
  int cq = idx % COQ;
  int pg = idx / COQ;
  int co = cq*4;                 // within block's co slice
  int gco = co_base + co;        // global co
  int p0 = pg*NPIX;

  float acc[NPIX][4] = {};
  int iy0[NPIX], ix0[NPIX]; const float* base[NPIX]; bool pv[NPIX];
#pragma unroll
  for (int t=0;t<NPIX;t++){
    int p=p0+t; pv[t]=(p<total); int pp=pv[t]?p:0;
    int ox=pp%OW; int r=pp/OW; int oy=r%OH; int n=r/OH;
    iy0[t]=oy*STRIDE-PAD; ix0[t]=ox*STRIDE-PAD;
    base[t]=in+(size_t)n*H*W*CIN + ci_off;
  }

  auto stage = [&](int tap0){
    constexpr int TQ = TAPF/4;
    constexpr int V  = NTAP*TQ;
    for (int v=threadIdx.x; v<V; v+=256){
      int tap = v / TQ; int rem = v - tap*TQ;
      float4 q;
      if constexpr (CS==1){
        const float4* src = (const float4*)(w + ((size_t)(tap0+tap)*CIN + ci_off)*COUT);
        q = src[rem];
      } else if constexpr (CLEN==3){
        int ci = rem / (COB/4); int r2 = rem - ci*(COB/4);
        q = *(const float4*)(w + ((size_t)(tap0+tap)*CIN + ci)*COUT
                               + co_base + r2*4);
      } else {
        int ci = rem / (COB/4); int r2 = rem - ci*(COB/4);
        q = *(const float4*)(w + ((size_t)(tap0+tap)*CIN + ci_off + ci)*COUT
                               + co_base + r2*4);
      }
      *(float4*)(sw + (size_t)tap*TAPF + rem*4) = q;
    }
  };

  if constexpr (SALL){
    stage(0);
    __syncthreads();
  }

  if constexpr (TOW>0){
    // ---- row-band LDS path ----
    const int pb0 = bx * ((256/COQ)*NPIX);   // first pixel of this block
    const int r0  = pb0 / TOW;               // first output row index (global)
    const int oy0 = r0 % OH;
    const int n0  = r0 / OH;                 // ROWS rows never cross n
    int myrow[NPIX], oxl[NPIX];
#pragma unroll
    for (int t=0;t<NPIX;t++){
      int pl = p0 + t - pb0;
      myrow[t] = pl / TOW;
      oxl[t]   = pl - myrow[t]*TOW;
    }

    for (int ky=0; ky<KH; ky++){
      __syncthreads();
      if constexpr (!SALL) stage(ky*KW);
      if constexpr (CLEN==3){
        constexpr int INS = ROWS*SPAN;
        for (int v=(int)threadIdx.x; v<INS; v+=256){
          int r  = v / SPAN;
          int ixo= v - r*SPAN;
          int iy = (oy0+r)*STRIDE - PAD + ky;
          int ix = ixo - PAD;
          bool ok = iy>=0 && iy<H && ix>=0 && ix<W;
          const float* ip = in + ((size_t)(n0*H+iy)*W + ix)*CIN;
          si[v*3+0] = ok?ip[0]:0.f;
          si[v*3+1] = ok?ip[1]:0.f;
          si[v*3+2] = ok?ip[2]:0.f;
        }
      } else {
        constexpr int INQ = ROWS*CQ4*SPAN;
        for (int v=(int)threadIdx.x; v<INQ; v+=256){
          int r  = v / (CQ4*SPAN);
          int rm = v - r*(CQ4*SPAN);
          int q  = rm / SPAN;
          int ixo= rm - q*SPAN;
          int iy = (oy0+r)*STRIDE - PAD + ky;
          int ix = ixo - PAD;
          bool ok = iy>=0 && iy<H && ix>=0 && ix<W;
          float4 val = ok ? *(const float4*)(in + ((size_t)(n0*H+iy)*W + ix)*CIN + ci_off + q*4)
                          : make_float4(0.f,0.f,0.f,0.f);
          *(float4*)&si[(size_t)v*4] = val;
        }
      }
      __syncthreads();
      const float* swr = SALL ? sw + (size_t)ky*KW*TAPF : sw;
      for (int kx=0; kx<KW; kx++){
        const float* swt = swr + (size_t)kx*TAPF;
        if constexpr (CLEN==3){
          float wv[3][4];
          *(float4*)wv[0]=*(const float4*)(swt + 0*COB + co);
          *(float4*)wv[1]=*(const float4*)(swt + 1*COB + co);
          *(float4*)wv[2]=*(const float4*)(swt + 2*COB + co);
#pragma unroll
          for (int t=0;t<NPIX;t++){
            const float* sp = &si[(size_t)(myrow[t]*SPAN + oxl[t]*STRIDE + kx)*3];
            float v0=sp[0], v1=sp[1], v2=sp[2];
#pragma unroll
            for (int j=0;j<4;j++)
              acc[t][j]=fmaf(v0,wv[0][j],fmaf(v1,wv[1][j],fmaf(v2,wv[2][j],acc[t][j])));
          }
        } else {
#pragma unroll 2
          for (int c=0; c<CQ4; c++){
            float wv[4][4];
#pragma unroll
            for (int r=0;r<4;r++)
              *(float4*)wv[r] = *(const float4*)(swt + (c*4+r)*COB + co);
#pragma unroll
            for (int t=0;t<NPIX;t++){
              float va[4];
              *(float4*)va = *(const float4*)&si[(size_t)((myrow[t]*CQ4 + c)*SPAN + oxl[t]*STRIDE + kx)*4];
#pragma unroll
              for (int r=0;r<4;r++)
#pragma unroll
                for (int j=0;j<4;j++)
                  acc[t][j]=fmaf(va[r],wv[r][j],acc[t][j]);
            }
          }
        }
      }
    }
  } else {
    // ---- r8-EXACT path ----
    for (int ky=0; ky<KH; ky++){
      if constexpr (!SALL){
        __syncthreads();
        stage(ky*KW);
        __syncthreads();
      }
      const float* swr = SALL ? sw + (size_t)ky*KW*TAPF : sw;
      for (int kx=0; kx<KW; kx++){
        const float* swt = swr + (size_t)kx*TAPF;
        const float* ip[NPIX]; bool ok[NPIX];
#pragma unroll
        for (int t=0;t<NPIX;t++){
          int iy=iy0[t]+ky, ix=ix0[t]+kx;
          ok[t]=pv[t] && iy>=0 && iy<H && ix>=0 && ix<W;
          ip[t]=base[t]+(size_t)(iy*W+ix)*CIN;
        }
        if constexpr (CLEN==3){
          float wv[3][4];
          *(float4*)wv[0]=*(const float4*)(swt + 0*COB + co);
          *(float4*)wv[1]=*(const float4*)(swt + 1*COB + co);
          *(float4*)wv[2]=*(const float4*)(swt + 2*COB + co);
#pragma unroll
          for (int t=0;t<NPIX;t++){
            float v0=ok[t]?ip[t][0]:0.f;
            float v1=ok[t]?ip[t][1]:0.f;
            float v2=ok[t]?ip[t][2]:0.f;
#pragma unroll
            for (int j=0;j<4;j++)
              acc[t][j]=fmaf(v0,wv[0][j],fmaf(v1,wv[1][j],fmaf(v2,wv[2][j],acc[t][j])));
          }
        } else {
#pragma unroll 2
          for (int ci=0; ci<CLEN; ci+=4){
            float wv[4][4];
#pragma unroll
            for (int r=0;r<4;r++)
              *(float4*)wv[r] = *(const float4*)(swt + (ci+r)*COB + co);
#pragma unroll
            for (int t=0;t<NPIX;t++){
              float va[4];
              *(float4*)va = ok[t] ? *(const float4*)(ip[t]+ci)
                                   : make_float4(0.f,0.f,0.f,0.f);
#pragma unroll
              for (int r=0;r<4;r++)
#pragma unroll
                for (int j=0;j<4;j++)
                  acc[t][j]=fmaf(va[r],wv[r][j],acc[t][j]);
            }
          }
        }
      }
    }
  }

  float bv[4]={0.f,0.f,0.f,0.f};
  if constexpr (BIAS) *(float4*)bv = *(const float4*)(bias+gco);
#pragma unroll
  for (int t=0;t<NPIX;t++) if (pv[t]){
    float o[4];
#pragma unroll
    for (int j=0;j<4;j++){
      float v = acc[t][j]+bv[j];
      o[j] = ACT ? silu_f(v) : v;
    }
    *(float4*)(out + (size_t)(p0+t)*COUT + gco) = *(float4*)o;
  }
}

// ---------------------------------------------------------------------------
// reduce G partials (stride n) + bias + optional silu. (FROZEN)
// ---------------------------------------------------------------------------
template<int G,int COUT,bool ACT>
__global__ __launch_bounds__(256) void reduce_k(
    const float* __restrict__ p, const float* __restrict__ bias,
    float* __restrict__ out, int n)
{
  int i = (blockIdx.x*256+threadIdx.x)*4;
  if (i>=n) return;
  float a[4]; *(float4*)a = *(const float4*)(p+i);
#pragma unroll
  for (int g=1; g<G; g++){
    float b[4]; *(float4*)b = *(const float4*)(p+(size_t)g*n+i);
#pragma unroll
    for (int j=0;j<4;j++) a[j]+=b[j];
  }
  float bv[4]; *(float4*)bv = *(const float4*)(bias + (i % COUT));
#pragma unroll
  for (int j=0;j<4;j++){
    float v=a[j]+bv[j];
    a[j] = ACT ? silu_f(v) : v;
  }
  *(float4*)(out+i) = *(float4*)a;
}

// ---------------------------------------------------------------------------
// conv_transpose 5x5 s2 SAME (verified r0 mapping), per-tap LDS weight stage.
// parity = b&3, ci-group = (b>>2)&(G-1), spatial = b>>(2+GSH). r8-EXACT.
// ---------------------------------------------------------------------------
template<int CIN,int COUT,int NPIX,int G,bool DIRECT>
__global__ __launch_bounds__(256) void tconv_k(
    const float* __restrict__ in, const float* __restrict__ w,
    const float* __restrict__ bias, float* __restrict__ out,
    int N,int H,int W,int OH,int OW)
{
  constexpr int COQ  = COUT/4;
  constexpr int CLEN = CIN/G;
  constexpr int GSH  = LOG2<G>::v;
  constexpr int TAPF = CLEN*COUT;
  __shared__ float sw[TAPF];
  const int par = blockIdx.x & 3;
  const int py = par>>1, px = par&1;
  const int g  = (blockIdx.x>>2) & (G-1);
  const int bx = blockIdx.x >> (2+GSH);
  const int NKY = py?3:2, NKX = px?3:2;
  const int OHh=OH>>1, OWh=OW>>1;
  const int total = N*OHh*OWh;
  if (G>1) out += (size_t)g * N*OH*OW*COUT;

  int idx = bx*256 + (int)threadIdx.x;
  int cq = idx % COQ;
  int pg = idx / COQ;
  int co = cq*4;
  int p0 = pg*NPIX;

  float acc[NPIX][4] = {};
  int yy[NPIX], xx[NPIX], nn[NPIX]; const float* base[NPIX]; bool pv[NPIX];
#pragma unroll
  for (int t=0;t<NPIX;t++){
    int p=p0+t; pv[t]=(p<total); int pp=pv[t]?p:0;
    xx[t]=pp%OWh; int r=pp/OWh; yy[t]=r%OHh; nn[t]=r/OHh;
    base[t]=in+(size_t)nn[t]*H*W*CIN + g*CLEN;
  }

  for (int j=0;j<NKY;j++){
    int ky = 2*j + (py?0:1);
    for (int i=0;i<NKX;i++){
      int kx = 2*i + (px?0:1);
      __syncthreads();
      {
        constexpr int V = TAPF/4;
        const float4* src = (const float4*)(w + ((size_t)(ky*5+kx)*CIN + g*CLEN)*COUT);
        for (int v=threadIdx.x; v<V; v+=256) ((float4*)sw)[v]=src[v];
      }
      __syncthreads();
      const float* ip[NPIX]; bool ok[NPIX];
#pragma unroll
      for (int t=0;t<NPIX;t++){
        int iy=yy[t]+j-1, ix=xx[t]+i-1;
        ok[t]=pv[t] && iy>=0 && iy<H && ix>=0 && ix<W;
        ip[t]=base[t]+(size_t)(iy*W+ix)*CIN;
      }
#pragma unroll 2
      for (int ci=0; ci<CLEN; ci+=4){
        float wv[4][4];
#pragma unroll
        for (int r=0;r<4;r++)
          *(float4*)wv[r] = *(const float4*)(sw + (ci+r)*COUT + co);
#pragma unroll
        for (int t=0;t<NPIX;t++){
          float va[4];
          *(float4*)va = ok[t] ? *(const float4*)(ip[t]+ci)
                               : make_float4(0.f,0.f,0.f,0.f);
#pragma unroll
          for (int r=0;r<4;r++)
#pragma unroll
            for (int jj=0;jj<4;jj++)
              acc[t][jj]=fmaf(va[r],wv[r][jj],acc[t][jj]);
        }
      }
    }
  }

  float bv[4]={0.f,0.f,0.f,0.f};
  if constexpr (DIRECT) *(float4*)bv = *(const float4*)(bias+co);
#pragma unroll
  for (int t=0;t<NPIX;t++) if (pv[t]){
    float o[4];
#pragma unroll
    for (int jj=0;jj<4;jj++){
      float v = acc[t][jj]+bv[jj];
      o[jj] = DIRECT ? silu_f(v) : v;
    }
    *(float4*)(out + (((size_t)nn[t]*OH + (2*yy[t]+py))*OW + (2*xx[t]+px))*COUT + co) = *(float4*)o;
  }
}

// ---------------------------------------------------------------------------
// VQ fused with conv3c 2-partial reduction + bias (round-2 EXACT — FROZEN).
// ---------------------------------------------------------------------------
__global__ __launch_bounds__(256) void vq_k(
    const float* __restrict__ p, const float* __restrict__ bias,
    const float* __restrict__ cb, float* __restrict__ q, int NLat)
{
  __shared__ float slat[4][128];
  int wave = threadIdx.x >> 6;
  int lane = threadIdx.x & 63;
  int l = blockIdx.x*4 + wave;
  if (l >= NLat) return;
  const float* p0 = p + (size_t)l*128;
  const float* p1 = p0 + (size_t)NLat*128;
  slat[wave][lane]    = p0[lane]    + p1[lane]    + bias[lane];
  slat[wave][lane+64] = p0[lane+64] + p1[lane+64] + bias[lane+64];

  float bestd = INFINITY; int besti = 0;
  for (int c0=0;c0<256;c0+=64){
    int c = c0 + lane;
    const float* cp = cb + (size_t)c*128;
    float d = 0.f;
#pragma unroll 8
    for (int k=0;k<128;k+=4){
      float4 cv = *reinterpret_cast<const float4*>(cp+k);
      float d0 = slat[wave][k+0]-cv.x;
      float d1 = slat[wave][k+1]-cv.y;
      float d2 = slat[wave][k+2]-cv.z;
      float d3 = slat[wave][k+3]-cv.w;
      d += d0*d0; d += d1*d1; d += d2*d2; d += d3*d3;
    }
    if (d < bestd) { bestd = d; besti = c; }
  }
  for (int off=32; off; off>>=1){
    float od = __shfl_down(bestd, off);
    int   oi = __shfl_down(besti, off);
    if (od < bestd || (od == bestd && oi < besti)) { bestd=od; besti=oi; }
  }
  besti = __shfl(besti, 0);
  const float* cp = cb + (size_t)besti*128;
  float* qp = q + (size_t)l*128;
  qp[lane]    = cp[lane];
  qp[lane+64] = cp[lane+64];
}

// ---------------------------------------------------------------------------
// Final 3x3 conv 32->3 split over ky rows (g = blockIdx%3). Writes partials.
// ---------------------------------------------------------------------------
__global__ __launch_bounds__(256) void conv_last_k(
    const float* __restrict__ in, const float* __restrict__ w,
    float* __restrict__ p, int N,int H,int W)
{
  int g = blockIdx.x % 3;
  int bx = blockIdx.x / 3;
  int pix = bx*256 + threadIdx.x;
  int total = N*H*W;
  if (pix>=total) return;
  int x = pix % W; int r = pix / W; int y = r % H; int n = r / H;
  float a0=0.f, a1=0.f, a2=0.f;
  int iy = y + g - 1;
  if (iy>=0 && iy<H){
    const float* base = in + ((size_t)n*H + iy)*W*32;
    for (int kx=0;kx<3;kx++){
      int ix=x+kx-1; if(ix<0||ix>=W) continue;
      const float* ip = base + (size_t)ix*32;
      const float* wp = w + (size_t)((g*3+kx)*32)*3;
#pragma unroll
      for (int ci=0;ci<32;ci+=4){
        float va[4]; *(float4*)va = *(const float4*)(ip+ci);
        float wv[12];
        *(float4*)(wv+0) = *(const float4*)(wp+ci*3+0);
        *(float4*)(wv+4) = *(const float4*)(wp+ci*3+4);
        *(float4*)(wv+8) = *(const float4*)(wp+ci*3+8);
#pragma unroll
        for (int r2=0;r2<4;r2++){
          a0 = fmaf(va[r2], wv[r2*3+0], a0);
          a1 = fmaf(va[r2], wv[r2*3+1], a1);
          a2 = fmaf(va[r2], wv[r2*3+2], a2);
        }
      }
    }
  }
  float* pp = p + (size_t)g*total*3 + (size_t)pix*3;
  pp[0]=a0; pp[1]=a1; pp[2]=a2;
}

__global__ __launch_bounds__(256) void reduce_last_k(
    const float* __restrict__ p, const float* __restrict__ bias,
    float* __restrict__ out, int n)
{
  int i = (blockIdx.x*256+threadIdx.x)*4;
  if (i>=n) return;
  float a[4]; *(float4*)a = *(const float4*)(p+i);
#pragma unroll
  for (int g=1; g<3; g++){
    float b[4]; *(float4*)b = *(const float4*)(p+(size_t)g*n+i);
#pragma unroll
    for (int j=0;j<4;j++) a[j]+=b[j];
  }
  float o[4];
#pragma unroll
  for (int j=0;j<4;j++) o[j] = a[j] + bias[(i+j)%3];
  *(float4*)(out+i) = *(float4*)o;
}

extern "C" void kernel_launch(void* const* d_in, const int* in_sizes, int n_in,
                              void* d_out, int out_size, void* d_ws, size_t ws_size,
                              hipStream_t stream) {
  const float* x    = (const float*)d_in[0];
  const float* k1   = (const float*)d_in[1];  const float* b1  = (const float*)d_in[2];
  const float* k1c  = (const float*)d_in[3];  const float* b1c = (const float*)d_in[4];
  const float* k2   = (const float*)d_in[5];  const float* b2  = (const float*)d_in[6];
  const float* k2c  = (const float*)d_in[7];  const float* b2c = (const float*)d_in[8];
  const float* k3   = (const float*)d_in[9];  const float* b3  = (const float*)d_in[10];
  const float* k3c  = (const float*)d_in[11]; const float* b3c = (const float*)d_in[12];
  const float* cb   = (const float*)d_in[13];
  const float* tk1  = (const float*)d_in[14]; const float* tb1  = (const float*)d_in[15];
  const float* tk1c = (const float*)d_in[16]; const float* tb1c = (const float*)d_in[17];
  const float* tk2  = (const float*)d_in[18]; const float* tb2  = (const float*)d_in[19];
  const float* tk2c = (const float*)d_in[20]; const float* tb2c = (const float*)d_in[21];
  const float* tk3  = (const float*)d_in[22]; const float* tb3  = (const float*)d_in[23];
  const float* tk3c = (const float*)d_in[24]; const float* tb3c = (const float*)d_in[25];
  float* out = (float*)d_out;

  float* S  = (float*)d_ws;
  float* W0 = S;                 // [0 .. 1M) floats
  float* W1 = S + 1048576;       // [1M .. 2M)
  float* P  = S + 2097152;       // [2M .. 6M)
  dim3 blk(256);

  // ---- encoder: G-splits + fmaf order FROZEN; TOW row-band + NPIX=2 ----
  // conv1: NPIX=2 -> 2 rows/block; sw SALL 23.2KB + si 3.3KB; 512 blocks
  conv_k<11,11,2,4,  3, 32,2,true ,true ,1,2,64><<< 512,blk,0,stream>>>(x,  k1,  b1,  W0, 8,128,128,64,64);
  // conv1c: NPIX=2 -> 2 rows/block; sw SALL 18KB + si 16.9KB; 512 blocks
  conv_k< 3, 3,1,1, 32, 32,2,true ,true ,1,2,64><<< 512,blk,0,stream>>>(W0, k1c, b1c, W1, 8,64,64,64,64);
  // conv2: NPIX=2 (r16-proven); per-ky sw 22.5KB + si 9.3KB; 512 blocks
  conv_k<11,11,2,4, 32, 64,2,false,false,2,2,32><<< 512,blk,0,stream>>>(W1, k2,  nullptr, P, 8,64,64,32,32);
  reduce_k<2, 64,true><<< 512,blk,0,stream>>>(P, b2,  W0, 524288);
  // conv2c: NPIX=1 (grid floor); per-ky sw 24KB + si 8.5KB; 512 blocks
  conv_k< 3, 3,1,1, 64, 64,1,true ,true ,1,2,32><<< 512,blk,0,stream>>>(W0, k2c, b2c, W1, 8,32,32,32,32);
  // conv3: NPIX=2 (r16-proven); per-ky sw 22.5KB + si 10.5KB; 512 blocks
  conv_k<11,11,2,4, 64,128,2,false,false,4,4,16><<< 512,blk,0,stream>>>(W1, k3,  nullptr, P, 8,32,32,16,16);
  reduce_k<4,128,true><<< 256,blk,0,stream>>>(P, b3,  W0, 262144);
  // conv3c: NPIX=1 (grid floor); per-ky sw 24KB + si 9.2KB; 512 blocks
  conv_k< 3, 3,1,1,128,128,1,false,false,2,4,16><<< 512,blk,0,stream>>>(W0, k3c, nullptr, P, 8,16,16,16,16);
  // ---- VQ: r2-exact 2-partial reduce + argmin + gather (FROZEN) ----
  vq_k<<<512,blk,0,stream>>>(P, b3c, cb, W1, 2048);
  // ---- decoder (tconvs r8-exact; 3x3s row-banded, NPIX=2 where grid>=512) ----
  tconv_k<128,64,1,4,false><<<2048,blk,0,stream>>>(W1, tk1, nullptr, P, 8,16,16,32,32);
  reduce_k<4, 64,true><<< 512,blk,0,stream>>>(P, tb1,  W0, 524288);
  // tk1c: NPIX=2 -> 4 rows/block; sw SALL 18KB + si 17.4KB; 512 blocks
  conv_k< 3, 3,1,1, 64, 64,2,false,false,2,4,32><<< 512,blk,0,stream>>>(W0, tk1c, nullptr, P, 8,32,32,32,32);
  reduce_k<2, 64,true><<< 512,blk,0,stream>>>(P, tb1c, W1, 524288);
  tconv_k< 64,32,1,2,false><<<2048,blk,0,stream>>>(W1, tk2, nullptr, P, 8,32,32,64,64);
  reduce_k<2, 32,true><<<1024,blk,0,stream>>>(P, tb2,  W0, 1048576);
  // tk2c: NPIX=2 -> 2 rows/block; sw SALL 18KB + si 16.9KB; 512 blocks
  conv_k< 3, 3,1,1, 32, 32,2,true ,true ,1,2,64><<< 512,blk,0,stream>>>(W0, tk2c, tb2c, W1, 8,64,64,64,64);
  tconv_k< 32,32,2,1,true ><<<2048,blk,0,stream>>>(W1, tk3, tb3, P, 8,64,64,128,128);
  conv_last_k<<<1536,blk,0,stream>>>(P, tk3c, S, 8,128,128);
  reduce_last_k<<<384,blk,0,stream>>>(S, tb3c, out, 393216);
}

// Round 18
// 450.470 us; speedup vs baseline: 9.5760x; 1.0271x over previous
//
#include <hip/hip_runtime.h>

#define DI __device__ __forceinline__
DI float silu_f(float x){ return x * (1.0f/(1.0f+__expf(-x))); }

template<int X> struct LOG2 { static constexpr int v = 1 + LOG2<X/2>::v; };
template<> struct LOG2<1> { static constexpr int v = 0; };

// ---------------------------------------------------------------------------
// Direct conv (r17-EXACT). G FROZEN (VQ argmin rounding). TOW row-band LDS.
// ---------------------------------------------------------------------------
template<int KH,int KW,int STRIDE,int PAD,int CIN,int COUT,int NPIX,
         bool ACT,bool BIAS,int G,int CS,int TOW>
__global__ __launch_bounds__(256) void conv_k(
    const float* __restrict__ in, const float* __restrict__ w,
    const float* __restrict__ bias, float* __restrict__ out,
    int N,int H,int W,int OH,int OW)
{
  constexpr int CLEN = CIN/G;
  constexpr int COB  = COUT/CS;
  constexpr int COQ  = COB/4;
  constexpr int GSH  = LOG2<G>::v;
  constexpr int CSH  = LOG2<CS>::v;
  constexpr int TAPF = CLEN*COB;
  constexpr bool SALL = (KH*KW*TAPF*4) <= 47*1024;
  constexpr int NTAP = SALL ? KH*KW : KW;
  static_assert(CLEN==3 || (CLEN%4)==0, "ci");
  __shared__ float sw[NTAP*TAPF];
  constexpr int SPAN = (TOW>0) ? (TOW-1)*STRIDE + KW : 1;
  constexpr int ROWS = (TOW>0) ? ((256/COQ)*NPIX)/TOW : 1;
  constexpr int CQ4  = (TOW>0 && CLEN!=3) ? CLEN/4 : 1;
  constexpr int SI_F = (TOW==0) ? 1 : (CLEN==3 ? ROWS*SPAN*3 : ROWS*CQ4*SPAN*4);
  __shared__ float si[SI_F];
  static_assert(TOW==0 || NPIX<=2, "tow npix");
  static_assert(TOW==0 || ((256/COQ)*NPIX) % TOW == 0, "rows");

  const int g  = blockIdx.x & (G-1);
  const int cs = (blockIdx.x >> GSH) & (CS-1);
  const int bx = blockIdx.x >> (GSH+CSH);
  const int total = N*OH*OW;
  if (G>1) out += (size_t)g * total * COUT;
  const int ci_off  = g*CLEN;
  const int co_base = cs*COB;

  int idx = bx*256 + (int)threadIdx.x;
  int cq = idx % COQ;
  int pg = idx / COQ;
  int co = cq*4;
  int gco = co_base + co;
  int p0 = pg*NPIX;

  float acc[NPIX][4] = {};
  int iy0[NPIX], ix0[NPIX]; const float* base[NPIX]; bool pv[NPIX];
#pragma unroll
  for (int t=0;t<NPIX;t++){
    int p=p0+t; pv[t]=(p<total); int pp=pv[t]?p:0;
    int ox=pp%OW; int r=pp/OW; int oy=r%OH; int n=r/OH;
    iy0[t]=oy*STRIDE-PAD; ix0[t]=ox*STRIDE-PAD;
    base[t]=in+(size_t)n*H*W*CIN + ci_off;
  }

  auto stage = [&](int tap0){
    constexpr int TQ = TAPF/4;
    constexpr int V  = NTAP*TQ;
    for (int v=threadIdx.x; v<V; v+=256){
      int tap = v / TQ; int rem = v - tap*TQ;
      float4 q;
      if constexpr (CS==1){
        const float4* src = (const float4*)(w + ((size_t)(tap0+tap)*CIN + ci_off)*COUT);
        q = src[rem];
      } else if constexpr (CLEN==3){
        int ci = rem / (COB/4); int r2 = rem - ci*(COB/4);
        q = *(const float4*)(w + ((size_t)(tap0+tap)*CIN + ci)*COUT
                               + co_base + r2*4);
      } else {
        int ci = rem / (COB/4); int r2 = rem - ci*(COB/4);
        q = *(const float4*)(w + ((size_t)(tap0+tap)*CIN + ci_off + ci)*COUT
                               + co_base + r2*4);
      }
      *(float4*)(sw + (size_t)tap*TAPF + rem*4) = q;
    }
  };

  if constexpr (SALL){
    stage(0);
    __syncthreads();
  }

  if constexpr (TOW>0){
    const int pb0 = bx * ((256/COQ)*NPIX);
    const int r0  = pb0 / TOW;
    const int oy0 = r0 % OH;
    const int n0  = r0 / OH;
    int myrow[NPIX], oxl[NPIX];
#pragma unroll
    for (int t=0;t<NPIX;t++){
      int pl = p0 + t - pb0;
      myrow[t] = pl / TOW;
      oxl[t]   = pl - myrow[t]*TOW;
    }

    for (int ky=0; ky<KH; ky++){
      __syncthreads();
      if constexpr (!SALL) stage(ky*KW);
      if constexpr (CLEN==3){
        constexpr int INS = ROWS*SPAN;
        for (int v=(int)threadIdx.x; v<INS; v+=256){
          int r  = v / SPAN;
          int ixo= v - r*SPAN;
          int iy = (oy0+r)*STRIDE - PAD + ky;
          int ix = ixo - PAD;
          bool ok = iy>=0 && iy<H && ix>=0 && ix<W;
          const float* ip = in + ((size_t)(n0*H+iy)*W + ix)*CIN;
          si[v*3+0] = ok?ip[0]:0.f;
          si[v*3+1] = ok?ip[1]:0.f;
          si[v*3+2] = ok?ip[2]:0.f;
        }
      } else {
        constexpr int INQ = ROWS*CQ4*SPAN;
        for (int v=(int)threadIdx.x; v<INQ; v+=256){
          int r  = v / (CQ4*SPAN);
          int rm = v - r*(CQ4*SPAN);
          int q  = rm / SPAN;
          int ixo= rm - q*SPAN;
          int iy = (oy0+r)*STRIDE - PAD + ky;
          int ix = ixo - PAD;
          bool ok = iy>=0 && iy<H && ix>=0 && ix<W;
          float4 val = ok ? *(const float4*)(in + ((size_t)(n0*H+iy)*W + ix)*CIN + ci_off + q*4)
                          : make_float4(0.f,0.f,0.f,0.f);
          *(float4*)&si[(size_t)v*4] = val;
        }
      }
      __syncthreads();
      const float* swr = SALL ? sw + (size_t)ky*KW*TAPF : sw;
      for (int kx=0; kx<KW; kx++){
        const float* swt = swr + (size_t)kx*TAPF;
        if constexpr (CLEN==3){
          float wv[3][4];
          *(float4*)wv[0]=*(const float4*)(swt + 0*COB + co);
          *(float4*)wv[1]=*(const float4*)(swt + 1*COB + co);
          *(float4*)wv[2]=*(const float4*)(swt + 2*COB + co);
#pragma unroll
          for (int t=0;t<NPIX;t++){
            const float* sp = &si[(size_t)(myrow[t]*SPAN + oxl[t]*STRIDE + kx)*3];
            float v0=sp[0], v1=sp[1], v2=sp[2];
#pragma unroll
            for (int j=0;j<4;j++)
              acc[t][j]=fmaf(v0,wv[0][j],fmaf(v1,wv[1][j],fmaf(v2,wv[2][j],acc[t][j])));
          }
        } else {
#pragma unroll 2
          for (int c=0; c<CQ4; c++){
            float wv[4][4];
#pragma unroll
            for (int r=0;r<4;r++)
              *(float4*)wv[r] = *(const float4*)(swt + (c*4+r)*COB + co);
#pragma unroll
            for (int t=0;t<NPIX;t++){
              float va[4];
              *(float4*)va = *(const float4*)&si[(size_t)((myrow[t]*CQ4 + c)*SPAN + oxl[t]*STRIDE + kx)*4];
#pragma unroll
              for (int r=0;r<4;r++)
#pragma unroll
                for (int j=0;j<4;j++)
                  acc[t][j]=fmaf(va[r],wv[r][j],acc[t][j]);
            }
          }
        }
      }
    }
  } else {
    for (int ky=0; ky<KH; ky++){
      if constexpr (!SALL){
        __syncthreads();
        stage(ky*KW);
        __syncthreads();
      }
      const float* swr = SALL ? sw + (size_t)ky*KW*TAPF : sw;
      for (int kx=0; kx<KW; kx++){
        const float* swt = swr + (size_t)kx*TAPF;
        const float* ip[NPIX]; bool ok[NPIX];
#pragma unroll
        for (int t=0;t<NPIX;t++){
          int iy=iy0[t]+ky, ix=ix0[t]+kx;
          ok[t]=pv[t] && iy>=0 && iy<H && ix>=0 && ix<W;
          ip[t]=base[t]+(size_t)(iy*W+ix)*CIN;
        }
        if constexpr (CLEN==3){
          float wv[3][4];
          *(float4*)wv[0]=*(const float4*)(swt + 0*COB + co);
          *(float4*)wv[1]=*(const float4*)(swt + 1*COB + co);
          *(float4*)wv[2]=*(const float4*)(swt + 2*COB + co);
#pragma unroll
          for (int t=0;t<NPIX;t++){
            float v0=ok[t]?ip[t][0]:0.f;
            float v1=ok[t]?ip[t][1]:0.f;
            float v2=ok[t]?ip[t][2]:0.f;
#pragma unroll
            for (int j=0;j<4;j++)
              acc[t][j]=fmaf(v0,wv[0][j],fmaf(v1,wv[1][j],fmaf(v2,wv[2][j],acc[t][j])));
          }
        } else {
#pragma unroll 2
          for (int ci=0; ci<CLEN; ci+=4){
            float wv[4][4];
#pragma unroll
            for (int r=0;r<4;r++)
              *(float4*)wv[r] = *(const float4*)(swt + (ci+r)*COB + co);
#pragma unroll
            for (int t=0;t<NPIX;t++){
              float va[4];
              *(float4*)va = ok[t] ? *(const float4*)(ip[t]+ci)
                                   : make_float4(0.f,0.f,0.f,0.f);
#pragma unroll
              for (int r=0;r<4;r++)
#pragma unroll
                for (int j=0;j<4;j++)
                  acc[t][j]=fmaf(va[r],wv[r][j],acc[t][j]);
            }
          }
        }
      }
    }
  }

  float bv[4]={0.f,0.f,0.f,0.f};
  if constexpr (BIAS) *(float4*)bv = *(const float4*)(bias+gco);
#pragma unroll
  for (int t=0;t<NPIX;t++) if (pv[t]){
    float o[4];
#pragma unroll
    for (int j=0;j<4;j++){
      float v = acc[t][j]+bv[j];
      o[j] = ACT ? silu_f(v) : v;
    }
    *(float4*)(out + (size_t)(p0+t)*COUT + gco) = *(float4*)o;
  }
}

// ---------------------------------------------------------------------------
// reduce G partials (stride n) + bias + optional silu. (FROZEN)
// ---------------------------------------------------------------------------
template<int G,int COUT,bool ACT>
__global__ __launch_bounds__(256) void reduce_k(
    const float* __restrict__ p, const float* __restrict__ bias,
    float* __restrict__ out, int n)
{
  int i = (blockIdx.x*256+threadIdx.x)*4;
  if (i>=n) return;
  float a[4]; *(float4*)a = *(const float4*)(p+i);
#pragma unroll
  for (int g=1; g<G; g++){
    float b[4]; *(float4*)b = *(const float4*)(p+(size_t)g*n+i);
#pragma unroll
    for (int j=0;j<4;j++) a[j]+=b[j];
  }
  float bv[4]; *(float4*)bv = *(const float4*)(bias + (i % COUT));
#pragma unroll
  for (int j=0;j<4;j++){
    float v=a[j]+bv[j];
    a[j] = ACT ? silu_f(v) : v;
  }
  *(float4*)(out+i) = *(float4*)a;
}

// ---------------------------------------------------------------------------
// conv_transpose 5x5 s2 SAME, r18 row-band version: block = whole output
// row(s) of one parity; stage ALL parity weight taps (<=9, <=37KB) + the
// full input row band (ROWS_O+2 rows, zero-padded) ONCE -> single barrier,
// then the entire j,i,ci tap loop is pure LDS (no barriers, no global loads,
// no bounds VALU). Per-output fmaf chain (j->i->ci asc->r asc) == old tconv.
// parity=b&3, g=(b>>2)&(G-1), cs=(b>>(2+GSH))&(CS-1), spatial=rest.
// ---------------------------------------------------------------------------
template<int CIN,int COUT,int NPIX,int G,int CS,int IW,bool DIRECT>
__global__ __launch_bounds__(256) void tconv_rb(
    const float* __restrict__ in, const float* __restrict__ w,
    const float* __restrict__ bias, float* __restrict__ out,
    int N,int H,int W,int OH,int OW)
{
  constexpr int CLEN = CIN/G;
  constexpr int COB  = COUT/CS;
  constexpr int COQ  = COB/4;
  constexpr int GSH  = LOG2<G>::v;
  constexpr int CSH  = LOG2<CS>::v;
  constexpr int TAPF = CLEN*COB;
  constexpr int PPB  = (256/COQ)*NPIX;     // pixels (half-res) per block
  static_assert(PPB % IW == 0, "whole rows");
  constexpr int ROWS_O = PPB/IW;
  constexpr int NRI  = ROWS_O + 2;         // input rows staged
  constexpr int SPAN = IW + 2;             // cols -1 .. IW
  constexpr int CQ4  = CLEN/4;
  __shared__ float sw[9*TAPF];
  __shared__ float si[NRI*CQ4*SPAN*4];

  const int par = blockIdx.x & 3;
  const int py = par>>1, px = par&1;
  const int g  = (blockIdx.x>>2) & (G-1);
  const int cs = (blockIdx.x>>(2+GSH)) & (CS-1);
  const int bx = blockIdx.x >> (2+GSH+CSH);
  const int NKY = py?3:2, NKX = px?3:2;
  const int OHh = OH>>1;
  if (G>1) out += (size_t)g * (size_t)N*OH*OW*COUT;
  const int co_base = cs*COB;

  const int tid = (int)threadIdx.x;
  int idx = bx*256 + tid;
  int cq = idx % COQ;
  int pg = idx / COQ;
  int co = cq*4;
  int p0 = pg*NPIX;
  const int pb0 = bx*PPB;
  const int R0  = pb0 / IW;
  const int oy0 = R0 % OHh;
  const int n0  = R0 / OHh;

  int myrow[NPIX], xx[NPIX];
#pragma unroll
  for (int t=0;t<NPIX;t++){
    int lp = p0 + t - pb0;
    myrow[t] = lp / IW;
    xx[t]    = lp - myrow[t]*IW;
  }

  // stage this parity's weight taps (slot j*3+i)
  {
    constexpr int TQ = TAPF/4;
    const int V = NKY*NKX*TQ;
    for (int v=tid; v<V; v+=256){
      int tap = v / TQ; int rem = v - tap*TQ;
      int j = tap / NKX, i = tap - j*NKX;
      int ky = 2*j + (py?0:1), kx = 2*i + (px?0:1);
      int ci = rem / (COB/4); int r2 = rem - ci*(COB/4);
      float4 q = *(const float4*)(w + ((size_t)(ky*5+kx)*CIN + g*CLEN + ci)*COUT
                                    + co_base + r2*4);
      *(float4*)(sw + (size_t)(j*3+i)*TAPF + rem*4) = q;
    }
  }
  // stage input rows oy0-1 .. oy0+ROWS_O, cols -1..IW (zero-padded)
  {
    constexpr int INQ = NRI*CQ4*SPAN;
    for (int v=tid; v<INQ; v+=256){
      int r  = v / (CQ4*SPAN);
      int rm = v - r*(CQ4*SPAN);
      int q  = rm / SPAN;
      int cc = rm - q*SPAN;
      int iy = oy0 - 1 + r;
      int ix = cc - 1;
      bool ok = iy>=0 && iy<H && ix>=0 && ix<W;
      float4 val = ok ? *(const float4*)(in + ((size_t)(n0*H+iy)*W + ix)*CIN + g*CLEN + q*4)
                      : make_float4(0.f,0.f,0.f,0.f);
      *(float4*)&si[(size_t)v*4] = val;
    }
  }
  __syncthreads();

  float acc[NPIX][4] = {};
  for (int j=0;j<NKY;j++){
    for (int i=0;i<NKX;i++){
      const float* swt = sw + (size_t)(j*3+i)*TAPF;
#pragma unroll 2
      for (int c=0;c<CQ4;c++){
        float wv[4][4];
#pragma unroll
        for (int r=0;r<4;r++)
          *(float4*)wv[r] = *(const float4*)(swt + (c*4+r)*COB + co);
#pragma unroll
        for (int t=0;t<NPIX;t++){
          float va[4];
          *(float4*)va = *(const float4*)&si[(size_t)(((myrow[t]+j)*CQ4 + c)*SPAN + (xx[t]+i))*4];
#pragma unroll
          for (int r=0;r<4;r++)
#pragma unroll
            for (int jj=0;jj<4;jj++)
              acc[t][jj]=fmaf(va[r],wv[r][jj],acc[t][jj]);
        }
      }
    }
  }

  float bv[4]={0.f,0.f,0.f,0.f};
  if constexpr (DIRECT) *(float4*)bv = *(const float4*)(bias+co_base+co);
#pragma unroll
  for (int t=0;t<NPIX;t++){
    float o[4];
#pragma unroll
    for (int jj=0;jj<4;jj++){
      float v = acc[t][jj]+bv[jj];
      o[jj] = DIRECT ? silu_f(v) : v;
    }
    *(float4*)(out + (((size_t)n0*OH + (2*(oy0+myrow[t])+py))*OW + (2*xx[t]+px))*COUT + co_base+co) = *(float4*)o;
  }
}

// ---------------------------------------------------------------------------
// VQ fused with conv3c 2-partial reduction + bias (round-2 EXACT — FROZEN).
// ---------------------------------------------------------------------------
__global__ __launch_bounds__(256) void vq_k(
    const float* __restrict__ p, const float* __restrict__ bias,
    const float* __restrict__ cb, float* __restrict__ q, int NLat)
{
  __shared__ float slat[4][128];
  int wave = threadIdx.x >> 6;
  int lane = threadIdx.x & 63;
  int l = blockIdx.x*4 + wave;
  if (l >= NLat) return;
  const float* p0 = p + (size_t)l*128;
  const float* p1 = p0 + (size_t)NLat*128;
  slat[wave][lane]    = p0[lane]    + p1[lane]    + bias[lane];
  slat[wave][lane+64] = p0[lane+64] + p1[lane+64] + bias[lane+64];

  float bestd = INFINITY; int besti = 0;
  for (int c0=0;c0<256;c0+=64){
    int c = c0 + lane;
    const float* cp = cb + (size_t)c*128;
    float d = 0.f;
#pragma unroll 8
    for (int k=0;k<128;k+=4){
      float4 cv = *reinterpret_cast<const float4*>(cp+k);
      float d0 = slat[wave][k+0]-cv.x;
      float d1 = slat[wave][k+1]-cv.y;
      float d2 = slat[wave][k+2]-cv.z;
      float d3 = slat[wave][k+3]-cv.w;
      d += d0*d0; d += d1*d1; d += d2*d2; d += d3*d3;
    }
    if (d < bestd) { bestd = d; besti = c; }
  }
  for (int off=32; off; off>>=1){
    float od = __shfl_down(bestd, off);
    int   oi = __shfl_down(besti, off);
    if (od < bestd || (od == bestd && oi < besti)) { bestd=od; besti=oi; }
  }
  besti = __shfl(besti, 0);
  const float* cp = cb + (size_t)besti*128;
  float* qp = q + (size_t)l*128;
  qp[lane]    = cp[lane];
  qp[lane+64] = cp[lane+64];
}

// ---------------------------------------------------------------------------
// Final 3x3 conv 32->3 split over ky rows (g = blockIdx%3). Writes partials.
// ---------------------------------------------------------------------------
__global__ __launch_bounds__(256) void conv_last_k(
    const float* __restrict__ in, const float* __restrict__ w,
    float* __restrict__ p, int N,int H,int W)
{
  int g = blockIdx.x % 3;
  int bx = blockIdx.x / 3;
  int pix = bx*256 + threadIdx.x;
  int total = N*H*W;
  if (pix>=total) return;
  int x = pix % W; int r = pix / W; int y = r % H; int n = r / H;
  float a0=0.f, a1=0.f, a2=0.f;
  int iy = y + g - 1;
  if (iy>=0 && iy<H){
    const float* base = in + ((size_t)n*H + iy)*W*32;
    for (int kx=0;kx<3;kx++){
      int ix=x+kx-1; if(ix<0||ix>=W) continue;
      const float* ip = base + (size_t)ix*32;
      const float* wp = w + (size_t)((g*3+kx)*32)*3;
#pragma unroll
      for (int ci=0;ci<32;ci+=4){
        float va[4]; *(float4*)va = *(const float4*)(ip+ci);
        float wv[12];
        *(float4*)(wv+0) = *(const float4*)(wp+ci*3+0);
        *(float4*)(wv+4) = *(const float4*)(wp+ci*3+4);
        *(float4*)(wv+8) = *(const float4*)(wp+ci*3+8);
#pragma unroll
        for (int r2=0;r2<4;r2++){
          a0 = fmaf(va[r2], wv[r2*3+0], a0);
          a1 = fmaf(va[r2], wv[r2*3+1], a1);
          a2 = fmaf(va[r2], wv[r2*3+2], a2);
        }
      }
    }
  }
  float* pp = p + (size_t)g*total*3 + (size_t)pix*3;
  pp[0]=a0; pp[1]=a1; pp[2]=a2;
}

__global__ __launch_bounds__(256) void reduce_last_k(
    const float* __restrict__ p, const float* __restrict__ bias,
    float* __restrict__ out, int n)
{
  int i = (blockIdx.x*256+threadIdx.x)*4;
  if (i>=n) return;
  float a[4]; *(float4*)a = *(const float4*)(p+i);
#pragma unroll
  for (int g=1; g<3; g++){
    float b[4]; *(float4*)b = *(const float4*)(p+(size_t)g*n+i);
#pragma unroll
    for (int j=0;j<4;j++) a[j]+=b[j];
  }
  float o[4];
#pragma unroll
  for (int j=0;j<4;j++) o[j] = a[j] + bias[(i+j)%3];
  *(float4*)(out+i) = *(float4*)o;
}

extern "C" void kernel_launch(void* const* d_in, const int* in_sizes, int n_in,
                              void* d_out, int out_size, void* d_ws, size_t ws_size,
                              hipStream_t stream) {
  const float* x    = (const float*)d_in[0];
  const float* k1   = (const float*)d_in[1];  const float* b1  = (const float*)d_in[2];
  const float* k1c  = (const float*)d_in[3];  const float* b1c = (const float*)d_in[4];
  const float* k2   = (const float*)d_in[5];  const float* b2  = (const float*)d_in[6];
  const float* k2c  = (const float*)d_in[7];  const float* b2c = (const float*)d_in[8];
  const float* k3   = (const float*)d_in[9];  const float* b3  = (const float*)d_in[10];
  const float* k3c  = (const float*)d_in[11]; const float* b3c = (const float*)d_in[12];
  const float* cb   = (const float*)d_in[13];
  const float* tk1  = (const float*)d_in[14]; const float* tb1  = (const float*)d_in[15];
  const float* tk1c = (const float*)d_in[16]; const float* tb1c = (const float*)d_in[17];
  const float* tk2  = (const float*)d_in[18]; const float* tb2  = (const float*)d_in[19];
  const float* tk2c = (const float*)d_in[20]; const float* tb2c = (const float*)d_in[21];
  const float* tk3  = (const float*)d_in[22]; const float* tb3  = (const float*)d_in[23];
  const float* tk3c = (const float*)d_in[24]; const float* tb3c = (const float*)d_in[25];
  float* out = (float*)d_out;

  float* S  = (float*)d_ws;
  float* W0 = S;                 // [0 .. 1M) floats
  float* W1 = S + 1048576;       // [1M .. 2M)
  float* P  = S + 2097152;       // [2M .. 6M)
  dim3 blk(256);

  // ---- encoder (r17-EXACT) ----
  conv_k<11,11,2,4,  3, 32,2,true ,true ,1,2,64><<< 512,blk,0,stream>>>(x,  k1,  b1,  W0, 8,128,128,64,64);
  conv_k< 3, 3,1,1, 32, 32,2,true ,true ,1,2,64><<< 512,blk,0,stream>>>(W0, k1c, b1c, W1, 8,64,64,64,64);
  conv_k<11,11,2,4, 32, 64,2,false,false,2,2,32><<< 512,blk,0,stream>>>(W1, k2,  nullptr, P, 8,64,64,32,32);
  reduce_k<2, 64,true><<< 512,blk,0,stream>>>(P, b2,  W0, 524288);
  conv_k< 3, 3,1,1, 64, 64,1,true ,true ,1,2,32><<< 512,blk,0,stream>>>(W0, k2c, b2c, W1, 8,32,32,32,32);
  conv_k<11,11,2,4, 64,128,2,false,false,4,4,16><<< 512,blk,0,stream>>>(W1, k3,  nullptr, P, 8,32,32,16,16);
  reduce_k<4,128,true><<< 256,blk,0,stream>>>(P, b3,  W0, 262144);
  conv_k< 3, 3,1,1,128,128,1,false,false,2,4,16><<< 512,blk,0,stream>>>(W0, k3c, nullptr, P, 8,16,16,16,16);
  // ---- VQ (FROZEN) ----
  vq_k<<<512,blk,0,stream>>>(P, b3c, cb, W1, 2048);
  // ---- decoder: tconvs single-stage row-band ----
  // tconv1 128->64 @16x16: G4 CS2 -> sw 36.9KB + si 9.2KB; 2048 blocks
  tconv_rb<128,64,1,4,2,16,false><<<2048,blk,0,stream>>>(W1, tk1, nullptr, P, 8,16,16,32,32);
  reduce_k<4, 64,true><<< 512,blk,0,stream>>>(P, tb1,  W0, 524288);
  conv_k< 3, 3,1,1, 64, 64,2,false,false,2,4,32><<< 512,blk,0,stream>>>(W0, tk1c, nullptr, P, 8,32,32,32,32);
  reduce_k<2, 64,true><<< 512,blk,0,stream>>>(P, tb1c, W1, 524288);
  // tconv2 64->32 @32x32: G2 CS1 -> sw 36.9KB + si 13KB; 2048 blocks
  tconv_rb< 64,32,1,2,1,32,false><<<2048,blk,0,stream>>>(W1, tk2, nullptr, P, 8,32,32,64,64);
  reduce_k<2, 32,true><<<1024,blk,0,stream>>>(P, tb2,  W0, 1048576);
  conv_k< 3, 3,1,1, 32, 32,2,true ,true ,1,2,64><<< 512,blk,0,stream>>>(W0, tk2c, tb2c, W1, 8,64,64,64,64);
  // tconv3 32->32 @64x64: G1 CS2 -> sw 18.4KB + si 25.3KB; 4096 blocks, direct
  tconv_rb< 32,32,1,1,2,64,true ><<<4096,blk,0,stream>>>(W1, tk3, tb3, P, 8,64,64,128,128);
  conv_last_k<<<1536,blk,0,stream>>>(P, tk3c, S, 8,128,128);
  reduce_last_k<<<384,blk,0,stream>>>(S, tb3c, out, 393216);
}